// Round 1
// baseline (7993.288 us; speedup 1.0000x reference)
//
#include <hip/hip_runtime.h>
#include <hip/hip_bf16.h>
#include <math.h>

#define LRELU 0.2f
#define BN_EPS 1e-5f
#define SN_EPS 1e-12f

// ---------------------------------------------------------------- reductions
__device__ inline float blockReduceSum256(float v, volatile float* red) {
  #pragma unroll
  for (int o = 32; o > 0; o >>= 1) v += __shfl_down(v, o, 64);
  const int tid = threadIdx.x;
  __syncthreads();                 // protect red across back-to-back uses
  if ((tid & 63) == 0) red[tid >> 6] = v;
  __syncthreads();
  return red[0] + red[1] + red[2] + red[3];
}

// ---------------------------------------------------------------- spectral norm
struct SNArgs {
  const float* w[6];
  const float* u[6];
  int outc[6];
  int ink[6];
};

// one block per layer; writes inv_sigma[l] = 1/sigma_l
__global__ __launch_bounds__(256) void sn_sigma_all(SNArgs args, float* __restrict__ inv_sigma) {
  const int l = blockIdx.x;
  const float* __restrict__ w = args.w[l];
  const float* __restrict__ u = args.u[l];
  const int out_c = args.outc[l];
  const int in_k  = args.ink[l];

  __shared__ float vS[8192];
  __shared__ float uS[512];
  __shared__ float red[4];

  const int tid = threadIdx.x;
  for (int i = tid; i < out_c; i += 256) uS[i] = u[i];
  __syncthreads();

  // t1 = wm^T u   (wm is [out_c, in_k])
  float lsq = 0.f;
  for (int j = tid; j < in_k; j += 256) {
    float t = 0.f;
    for (int i = 0; i < out_c; ++i) t = fmaf(w[(size_t)i * in_k + j], uS[i], t);
    vS[j] = t;
    lsq = fmaf(t, t, lsq);
  }
  const float n1 = blockReduceSum256(lsq, red);
  const float rinv = 1.f / (sqrtf(n1) + SN_EPS);
  __syncthreads();
  for (int j = tid; j < in_k; j += 256) vS[j] *= rinv;   // v
  __syncthreads();

  // t2 = wm v ; sigma = ||t2||^2 / (||t2|| + eps)
  float lsq2 = 0.f;
  const int q = tid & 3;
  const int jchunk = in_k >> 2;          // in_k divisible by 4 always (>=48)
  const int jb = jchunk * q;
  for (int i = (tid >> 2); i < out_c; i += 64) {
    float t = 0.f;
    const float* wrow = w + (size_t)i * in_k;
    for (int jj = 0; jj < jchunk; ++jj) {
      const int j = jb + jj;
      t = fmaf(wrow[j], vS[j], t);
    }
    t += __shfl_xor(t, 1, 64);
    t += __shfl_xor(t, 2, 64);
    if (q == 0) lsq2 = fmaf(t, t, lsq2);
  }
  const float n2sq = blockReduceSum256(lsq2, red);
  if (tid == 0) {
    const float n2 = sqrtf(n2sq);
    const float sigma = n2sq / (n2 + SN_EPS);
    inv_sigma[l] = 1.f / sigma;
  }
}

// ---------------------------------------------------------------- direct conv k4 s2 p1
// block (64 pixels, 4 co-groups); each thread computes 4 consecutive co.
__global__ __launch_bounds__(256) void conv_s2k4(
    const float* __restrict__ in, const float* __restrict__ w,
    const float* __restrict__ inv_sigma, float* __restrict__ out,
    int N, int Cin, int Hin, int Win, int Cout, int Hout, int Wout,
    int fuse_lrelu)
{
  const int tx = threadIdx.x;                 // 64
  const int ty = threadIdx.y;                 // 4
  const int HW = Hout * Wout;
  const int M = N * HW;
  int pix = blockIdx.x * 64 + tx;
  const bool active = (pix < M);
  if (!active) pix = 0;
  const int n  = pix / HW;
  const int hw = pix - n * HW;
  const int ho = hw / Wout;
  const int wo = hw - ho * Wout;
  const int co0 = (blockIdx.y * 4 + ty) * 4;  // 4 co per thread
  const int ih0 = 2 * ho - 1;
  const int iw0 = 2 * wo - 1;
  const float* __restrict__ inN = in + (size_t)n * Cin * Hin * Win;
  const int wCoStride = Cin * 16;
  const float* __restrict__ wB = w + (size_t)co0 * wCoStride;

  float a0 = 0.f, a1 = 0.f, a2 = 0.f, a3 = 0.f;
  for (int ci = 0; ci < Cin; ++ci) {
    const float* __restrict__ inC = inN + (size_t)ci * Hin * Win;
    const float* __restrict__ wC  = wB + ci * 16;
    #pragma unroll
    for (int kh = 0; kh < 4; ++kh) {
      const int ih = ih0 + kh;
      if ((unsigned)ih >= (unsigned)Hin) continue;
      const float* __restrict__ inR = inC + (size_t)ih * Win;
      #pragma unroll
      for (int kw = 0; kw < 4; ++kw) {
        const int iw = iw0 + kw;
        if ((unsigned)iw >= (unsigned)Win) continue;
        const float xv = inR[iw];
        const int widx = kh * 4 + kw;
        a0 = fmaf(xv, wC[widx], a0);
        a1 = fmaf(xv, wC[wCoStride + widx], a1);
        a2 = fmaf(xv, wC[2 * wCoStride + widx], a2);
        a3 = fmaf(xv, wC[3 * wCoStride + widx], a3);
      }
    }
  }
  if (!active) return;
  const float s = inv_sigma[0];
  float r[4] = {a0 * s, a1 * s, a2 * s, a3 * s};
  float* __restrict__ o = out + (size_t)(n * Cout + co0) * HW + hw;
  #pragma unroll
  for (int k = 0; k < 4; ++k) {
    float v = r[k];
    if (fuse_lrelu) v = (v >= 0.f) ? v : LRELU * v;
    o[(size_t)k * HW] = v;
  }
}

// ---------------------------------------------------------------- BN stats (one block per channel, deterministic)
__global__ __launch_bounds__(256) void bn_stats(const float* __restrict__ x, float* __restrict__ sums,
                                                int N, int C, int HW) {
  const int c = blockIdx.x;
  const int tid = threadIdx.x;
  __shared__ float red[4];
  float s = 0.f, s2 = 0.f;
  const int per = N * HW;
  for (int j = tid; j < per; j += 256) {
    const int n = j / HW;
    const int i = j - n * HW;
    const float v = x[((size_t)(n * C + c)) * HW + i];
    s += v;
    s2 = fmaf(v, v, s2);
  }
  const float ts  = blockReduceSum256(s, red);
  const float ts2 = blockReduceSum256(s2, red);
  if (tid == 0) { sums[c] = ts; sums[C + c] = ts2; }
}

// ---------------------------------------------------------------- BN normalize + LeakyReLU (in place)
__global__ __launch_bounds__(256) void bn_lrelu(float* __restrict__ x, const float* __restrict__ sums,
                                                const float* __restrict__ g, const float* __restrict__ b,
                                                int N, int C, int HW) {
  const float invM = 1.f / (float)(N * HW);
  const size_t total = (size_t)N * C * HW;
  for (size_t idx = (size_t)blockIdx.x * 256 + threadIdx.x; idx < total;
       idx += (size_t)gridDim.x * 256) {
    const int c = (int)((idx / (size_t)HW) % (size_t)C);
    const float m   = sums[c] * invM;
    const float var = sums[C + c] * invM - m * m;
    const float sc  = rsqrtf(var + BN_EPS) * g[c];
    float v = (x[idx] - m) * sc + b[c];
    x[idx] = (v >= 0.f) ? v : LRELU * v;
  }
}

// ---------------------------------------------------------------- Ms = flat @ T  (+ writes flat part of out)
__global__ __launch_bounds__(256) void ms_kernel(const float* __restrict__ x6, const float* __restrict__ T,
                                                 float* __restrict__ Ms, float* __restrict__ out) {
  const int n = blockIdx.x;       // 64
  const int tid = threadIdx.x;    // 256
  __shared__ float fs[256];
  const float f = x6[(size_t)n * 256 + tid];
  fs[tid] = f;
  out[(size_t)n * 320 + tid] = f;           // flat columns [0,256)
  __syncthreads();
  float acc[16];
  #pragma unroll
  for (int k = 0; k < 16; ++k) acc[k] = 0.f;
  for (int a = 0; a < 256; ++a) {
    const float fa = fs[a];
    const float* __restrict__ Trow = T + (size_t)a * 4096 + tid;
    #pragma unroll
    for (int k = 0; k < 16; ++k) acc[k] = fmaf(fa, Trow[(size_t)k * 256], acc[k]);
  }
  #pragma unroll
  for (int k = 0; k < 16; ++k) Ms[(size_t)n * 4096 + tid + (size_t)k * 256] = acc[k];
}

// ---------------------------------------------------------------- minibatch discrimination
__global__ __launch_bounds__(256) void mbd_kernel(const float* __restrict__ Ms, float* __restrict__ out) {
  const int b = blockIdx.x;       // 64
  const int tid = threadIdx.x;    // 256
  __shared__ float Mb[64][65];
  for (int idx = tid; idx < 4096; idx += 256) {
    const int i = idx >> 6, c = idx & 63;
    Mb[i][c] = Ms[(size_t)i * 4096 + b * 64 + c];
  }
  __syncthreads();
  const int i = tid >> 2, jj = tid & 3;
  float ssum = 0.f;
  for (int j = jj; j < 64; j += 4) {
    float d = 0.f;
    #pragma unroll
    for (int c = 0; c < 64; ++c) d += fabsf(Mb[i][c] - Mb[j][c]);
    ssum += expf(-d);
  }
  ssum += __shfl_xor(ssum, 1, 64);
  ssum += __shfl_xor(ssum, 2, 64);
  if (jj == 0) out[(size_t)i * 320 + 256 + b] = ssum;
}

// ---------------------------------------------------------------- launch
extern "C" void kernel_launch(void* const* d_in, const int* in_sizes, int n_in,
                              void* d_out, int out_size, void* d_ws, size_t ws_size,
                              hipStream_t stream) {
  const float* image = (const float*)d_in[0];
  const float* W[6] = {(const float*)d_in[1], (const float*)d_in[3], (const float*)d_in[5],
                       (const float*)d_in[7], (const float*)d_in[9], (const float*)d_in[11]};
  const float* U[6] = {(const float*)d_in[2], (const float*)d_in[4], (const float*)d_in[6],
                       (const float*)d_in[8], (const float*)d_in[10], (const float*)d_in[12]};
  const float* G[4] = {(const float*)d_in[13], (const float*)d_in[15],
                       (const float*)d_in[17], (const float*)d_in[19]};
  const float* Bb[4] = {(const float*)d_in[14], (const float*)d_in[16],
                        (const float*)d_in[18], (const float*)d_in[20]};
  const float* T = (const float*)d_in[21];
  float* out = (float*)d_out;
  float* ws = (float*)d_ws;

  // ws layout (floats)
  float* inv_sigma = ws;                        // [16]
  float* sums      = ws + 16;                   // [1024]  (sum[C], sumsq[C])
  float* Ms        = ws + 2048;                 // [262144]
  float* bufA      = ws + 2048 + 262144;        // [16777216]  x1/x3/x5
  float* bufB      = bufA + 16777216;           // [8388608]   x2/x4/x6

  // --- spectral norm sigmas (6 blocks, one launch)
  SNArgs sa;
  const int outc[6] = {64, 128, 256, 256, 512, 64};
  const int ink[6]  = {48, 1024, 2048, 4096, 4096, 8192};
  for (int l = 0; l < 6; ++l) { sa.w[l] = W[l]; sa.u[l] = U[l]; sa.outc[l] = outc[l]; sa.ink[l] = ink[l]; }
  sn_sigma_all<<<6, 256, 0, stream>>>(sa, inv_sigma);

  const int N = 64;
  const dim3 blk(64, 4);
  auto conv = [&](const float* src, int l, float* dst,
                  int Cin, int Cout, int Hin, int Hout, int fuse) {
    const int M = N * Hout * Hout;
    dim3 grid((M + 63) / 64, Cout / 16);
    conv_s2k4<<<grid, blk, 0, stream>>>(src, W[l], inv_sigma + l, dst,
                                        N, Cin, Hin, Hin, Cout, Hout, Hout, fuse);
  };
  auto bn = [&](float* x, int bi, int C, int HW) {
    bn_stats<<<C, 256, 0, stream>>>(x, sums, N, C, HW);
    const size_t total = (size_t)N * C * HW;
    int gs = (int)((total + 255) / 256);
    if (gs > 2048) gs = 2048;
    bn_lrelu<<<gs, 256, 0, stream>>>(x, sums, G[bi], Bb[bi], N, C, HW);
  };

  // L1: 3->64, 128->64, lrelu fused
  conv(image, 0, bufA, 3, 64, 128, 64, 1);
  // L2: 64->128, 64->32, BN+lrelu
  conv(bufA, 1, bufB, 64, 128, 64, 32, 0);
  bn(bufB, 0, 128, 32 * 32);
  // L3: 128->256, 32->16
  conv(bufB, 2, bufA, 128, 256, 32, 16, 0);
  bn(bufA, 1, 256, 16 * 16);
  // L4: 256->256, 16->8
  conv(bufA, 3, bufB, 256, 256, 16, 8, 0);
  bn(bufB, 2, 256, 8 * 8);
  // L5: 256->512, 8->4
  conv(bufB, 4, bufA, 256, 512, 8, 4, 0);
  bn(bufA, 3, 512, 4 * 4);
  // L6: 512->64, 4->2, plain
  conv(bufA, 5, bufB, 512, 64, 4, 2, 0);

  // tail: flat -> out[:, :256], Ms, MBD -> out[:, 256:320]
  ms_kernel<<<64, 256, 0, stream>>>(bufB, T, Ms, out);
  mbd_kernel<<<64, 256, 0, stream>>>(Ms, out);
}

// Round 2
// 1595.798 us; speedup vs baseline: 5.0090x; 5.0090x over previous
//
#include <hip/hip_runtime.h>
#include <hip/hip_bf16.h>
#include <math.h>

#define LRELU 0.2f
#define BN_EPS 1e-5f
#define SN_EPS 1e-12f

typedef __attribute__((ext_vector_type(4))) float f32x4;
typedef __attribute__((ext_vector_type(8))) short bf16x8;

__device__ inline float bf2f(short s) {
  union { unsigned u; float f; } c; c.u = ((unsigned)(unsigned short)s) << 16; return c.f;
}
__device__ inline short f2bf(float f) {
  __hip_bfloat16 h = __float2bfloat16(f); return *(short*)&h;
}

// ---------------------------------------------------------------- reductions
__device__ inline float blockReduceSum256(float v, volatile float* red) {
  #pragma unroll
  for (int o = 32; o > 0; o >>= 1) v += __shfl_down(v, o, 64);
  const int tid = threadIdx.x;
  __syncthreads();
  if ((tid & 63) == 0) red[tid >> 6] = v;
  __syncthreads();
  return red[0] + red[1] + red[2] + red[3];
}

// ---------------------------------------------------------------- spectral norm (proven round 1)
struct SNArgs {
  const float* w[6];
  const float* u[6];
  int outc[6];
  int ink[6];
};

__global__ __launch_bounds__(256) void sn_sigma_all(SNArgs args, float* __restrict__ inv_sigma) {
  const int l = blockIdx.x;
  const float* __restrict__ w = args.w[l];
  const float* __restrict__ u = args.u[l];
  const int out_c = args.outc[l];
  const int in_k  = args.ink[l];

  __shared__ float vS[8192];
  __shared__ float uS[512];
  __shared__ float red[4];

  const int tid = threadIdx.x;
  for (int i = tid; i < out_c; i += 256) uS[i] = u[i];
  __syncthreads();

  float lsq = 0.f;
  for (int j = tid; j < in_k; j += 256) {
    float t = 0.f;
    for (int i = 0; i < out_c; ++i) t = fmaf(w[(size_t)i * in_k + j], uS[i], t);
    vS[j] = t;
    lsq = fmaf(t, t, lsq);
  }
  const float n1 = blockReduceSum256(lsq, red);
  const float rinv = 1.f / (sqrtf(n1) + SN_EPS);
  __syncthreads();
  for (int j = tid; j < in_k; j += 256) vS[j] *= rinv;
  __syncthreads();

  float lsq2 = 0.f;
  const int q = tid & 3;
  const int jchunk = in_k >> 2;
  const int jb = jchunk * q;
  for (int i = (tid >> 2); i < out_c; i += 64) {
    float t = 0.f;
    const float* wrow = w + (size_t)i * in_k;
    for (int jj = 0; jj < jchunk; ++jj) {
      const int j = jb + jj;
      t = fmaf(wrow[j], vS[j], t);
    }
    t += __shfl_xor(t, 1, 64);
    t += __shfl_xor(t, 2, 64);
    if (q == 0) lsq2 = fmaf(t, t, lsq2);
  }
  const float n2sq = blockReduceSum256(lsq2, red);
  if (tid == 0) {
    const float n2 = sqrtf(n2sq);
    const float sigma = n2sq / (n2 + SN_EPS);
    inv_sigma[l] = 1.f / sigma;
  }
}

// ---------------------------------------------------------------- zero the OOB pad regions
__global__ __launch_bounds__(256) void zero_pads(__hip_bfloat16* r0, __hip_bfloat16* r1) {
  int t = blockIdx.x * 256 + threadIdx.x;
  if (t < 2048) {
    r0[16777216 + t] = __float2bfloat16(0.f);
    r1[16777216 + t] = __float2bfloat16(0.f);
  }
}

// ---------------------------------------------------------------- weight prepack into MFMA-fragment order
// dst layout: [K/32][COUT/16][64 lanes][8], value = B[k][co]*inv_sigma,
// k = khw*CINR + ci  (k >= KREAL -> 0 pad)
__global__ __launch_bounds__(256) void prepack_w(const float* __restrict__ w,
                                                 const float* __restrict__ invs,
                                                 __hip_bfloat16* __restrict__ dst,
                                                 int CINR, int COUT, int KPAD, int KREAL) {
  int e = blockIdx.x * 256 + threadIdx.x;
  if (e >= KPAD * COUT) return;
  int j = e & 7, lane = (e >> 3) & 63, frag = e >> 9;
  int nfrags = COUT >> 4;
  int ks = frag / nfrags, nf = frag - ks * nfrags;
  int k = ks * 32 + ((lane >> 4) << 3) + j;
  int co = (nf << 4) + (lane & 15);
  float val = 0.f;
  if (k < KREAL) {
    int khw = k / CINR, ci = k - khw * CINR;
    int kh = khw >> 2, kw = khw & 3;
    val = w[(((size_t)co * CINR + ci) * 4 + kh) * 4 + kw] * invs[0];
  }
  dst[e] = __float2bfloat16(val);
}

// L6 weights: dst[k][64co], k = khw*512 + ci
__global__ __launch_bounds__(256) void prepack_w6(const float* __restrict__ w,
                                                  const float* __restrict__ invs,
                                                  __hip_bfloat16* __restrict__ dst) {
  int e = blockIdx.x * 256 + threadIdx.x;   // 524288
  int k = e >> 6, co = e & 63;
  int khw = k >> 9, ci = k & 511;
  int kh = khw >> 2, kw = khw & 3;
  dst[e] = __float2bfloat16(w[(((size_t)co * 512 + ci) * 4 + kh) * 4 + kw] * invs[0]);
}

// ---------------------------------------------------------------- L1 im2col: image NCHW f32 -> [M=262144][64] bf16 (48 real k + 16 zeros)
__global__ __launch_bounds__(256) void im2col_l1(const float* __restrict__ img,
                                                 __hip_bfloat16* __restrict__ a2) {
  int m = blockIdx.x * 256 + threadIdx.x;      // 262144
  int n = m >> 12;
  int hw = m & 4095;
  int ho = hw >> 6, wo = hw & 63;
  int ihb = 2 * ho - 1, iwb = 2 * wo - 1;
  const float* ib = img + (size_t)n * 3 * 128 * 128;
  __hip_bfloat16* o = a2 + (size_t)m * 64;
  #pragma unroll
  for (int kh = 0; kh < 4; ++kh) {
    int ih = ihb + kh;
    bool vh = (unsigned)ih < 128u;
    #pragma unroll
    for (int kw = 0; kw < 4; ++kw) {
      int iw = iwb + kw;
      bool v = vh && ((unsigned)iw < 128u);
      int khw = kh * 4 + kw;
      #pragma unroll
      for (int ci = 0; ci < 3; ++ci) {
        float val = v ? ib[(size_t)ci * 16384 + ih * 128 + iw] : 0.f;
        o[khw * 3 + ci] = __float2bfloat16(val);
      }
    }
  }
  #pragma unroll
  for (int k = 48; k < 64; ++k) o[k] = __float2bfloat16(0.f);
}

// ---------------------------------------------------------------- MFMA implicit-GEMM conv (k4 s2 p1, or 1x1 for pre-im2col'd L1)
// A = im2col(x NHWC bf16) [M x K], B = prepacked weights [K x COUT].
// Block = 4 waves (2x2); wave tile = (MF*16) m x 32 co. No LDS: A gathered
// per-lane from global (L2/L3-resident), B streamed from fragment-ready layout.
template<int CIN, int COUT, int HIN, int HOUT, int KH, int MF, bool FUSE>
__global__ __launch_bounds__(256) void conv_mfma(
    const __hip_bfloat16* __restrict__ x,
    const __hip_bfloat16* __restrict__ wf,
    __hip_bfloat16* __restrict__ out)
{
  constexpr int WIN = HIN, WO = HOUT;
  constexpr int KHW = KH * KH;
  constexpr int CB = CIN / 32;
  constexpr int PADOFF = 16777216;   // zeroed pad region at end of each activation region

  const int lane = threadIdx.x & 63;
  const int wid  = threadIdx.x >> 6;
  const int wm = wid >> 1, wn = wid & 1;
  const int mbase = blockIdx.x * (MF * 32) + wm * (MF * 16);
  const int cobase = blockIdx.y * 64 + wn * 32;

  int offm[MF], ihb[MF], iwb[MF];
  #pragma unroll
  for (int mf = 0; mf < MF; ++mf) {
    int m = mbase + mf * 16 + (lane & 15);
    if (KH == 1) {
      ihb[mf] = 0; iwb[mf] = 0; offm[mf] = m * CIN;
    } else {
      int n = m / (HOUT * WO);
      int hw = m - n * (HOUT * WO);
      int ho = hw / WO, wo = hw - ho * WO;
      ihb[mf] = 2 * ho - 1;
      iwb[mf] = 2 * wo - 1;
      offm[mf] = ((n * HIN + ihb[mf]) * WIN + iwb[mf]) * CIN;
    }
  }
  const int koff = (lane >> 4) << 3;
  const __hip_bfloat16* wfp = wf + ((size_t)((blockIdx.y * 4 + wn * 2) * 64 + lane)) * 8;

  f32x4 acc[MF][2];
  #pragma unroll
  for (int mf = 0; mf < MF; ++mf) {
    acc[mf][0] = (f32x4){0.f, 0.f, 0.f, 0.f};
    acc[mf][1] = (f32x4){0.f, 0.f, 0.f, 0.f};
  }

  #pragma unroll
  for (int khw = 0; khw < KHW; ++khw) {
    const int kh = khw >> 2, kw = khw & 3;
    const __hip_bfloat16* ap[MF];
    #pragma unroll
    for (int mf = 0; mf < MF; ++mf) {
      int off;
      if (KH == 1) {
        off = offm[mf] + koff;
      } else {
        int ih = ihb[mf] + kh, iw = iwb[mf] + kw;
        bool v = ((unsigned)ih < (unsigned)HIN) & ((unsigned)iw < (unsigned)WIN);
        off = v ? (offm[mf] + (kh * WIN + kw) * CIN + koff) : (PADOFF + koff);
      }
      ap[mf] = x + off;
    }
    #pragma unroll
    for (int cb = 0; cb < CB; ++cb) {
      const int ks = khw * CB + cb;
      bf16x8 a[MF], b[2];
      #pragma unroll
      for (int mf = 0; mf < MF; ++mf) a[mf] = *(const bf16x8*)(ap[mf] + cb * 32);
      #pragma unroll
      for (int nf = 0; nf < 2; ++nf)
        b[nf] = *(const bf16x8*)(wfp + (size_t)ks * (COUT * 32) + nf * 512);
      #pragma unroll
      for (int mf = 0; mf < MF; ++mf)
        #pragma unroll
        for (int nf = 0; nf < 2; ++nf)
          acc[mf][nf] = __builtin_amdgcn_mfma_f32_16x16x32_bf16(a[mf], b[nf], acc[mf][nf], 0, 0, 0);
    }
  }

  // epilogue: C/D layout col=lane&15 (co), row=(lane>>4)*4+reg (pixel)
  const int r0 = (lane >> 4) * 4;
  const int cw = cobase + (lane & 15);
  #pragma unroll
  for (int mf = 0; mf < MF; ++mf)
    #pragma unroll
    for (int nf = 0; nf < 2; ++nf)
      #pragma unroll
      for (int r = 0; r < 4; ++r) {
        float v = acc[mf][nf][r];
        if (FUSE) v = (v >= 0.f) ? v : LRELU * v;
        int m = mbase + mf * 16 + r0 + r;
        out[(size_t)m * COUT + (cw + nf * 16)] = __float2bfloat16(v);
      }
}

// ---------------------------------------------------------------- BN stats (deterministic 2-stage), NHWC bf16
__global__ __launch_bounds__(256) void bn_stats_a(const __hip_bfloat16* __restrict__ x,
                                                  float* __restrict__ part, int M, int C) {
  const int chunk = blockIdx.x;              // 64 chunks
  const int c = blockIdx.y * 64 + (threadIdx.x & 63);
  const int msub = threadIdx.x >> 6;
  const int MC = M >> 6;
  float s = 0.f, s2 = 0.f;
  for (int mi = msub; mi < MC; mi += 4) {
    int m = chunk * MC + mi;
    float v = bf2f(*(const short*)&x[(size_t)m * C + c]);
    s += v;
    s2 = fmaf(v, v, s2);
  }
  __shared__ float ls[256], ls2[256];
  ls[threadIdx.x] = s; ls2[threadIdx.x] = s2;
  __syncthreads();
  if (msub == 0) {
    int t = threadIdx.x;
    s  = ls[t]  + ls[t + 64]  + ls[t + 128]  + ls[t + 192];
    s2 = ls2[t] + ls2[t + 64] + ls2[t + 128] + ls2[t + 192];
    part[(size_t)chunk * C + c] = s;
    part[(size_t)(64 + chunk) * C + c] = s2;
  }
}

__global__ __launch_bounds__(64) void bn_stats_b(const float* __restrict__ part,
                                                 const float* __restrict__ g,
                                                 const float* __restrict__ b,
                                                 float* __restrict__ sb, int M, int C) {
  int c = blockIdx.x * 64 + threadIdx.x;
  float s = 0.f, s2 = 0.f;
  for (int ch = 0; ch < 64; ++ch) { s += part[(size_t)ch * C + c]; s2 += part[(size_t)(64 + ch) * C + c]; }
  float invM = 1.f / (float)M;
  float mean = s * invM;
  float var = s2 * invM - mean * mean;
  float scale = g[c] * rsqrtf(var + BN_EPS);
  sb[c] = scale;
  sb[C + c] = b[c] - mean * scale;
}

__global__ __launch_bounds__(256) void bn_apply(__hip_bfloat16* __restrict__ x,
                                                const float* __restrict__ sb,
                                                int C, int nvec) {
  int idx = blockIdx.x * 256 + threadIdx.x;
  if (idx >= nvec) return;
  size_t e = (size_t)idx * 8;
  int c0 = (int)(e % (size_t)C);
  bf16x8 v = *(bf16x8*)(x + e);
  bf16x8 o;
  #pragma unroll
  for (int j = 0; j < 8; ++j) {
    int c = c0 + j;
    float f = bf2f(v[j]);
    f = fmaf(f, sb[c], sb[C + c]);
    f = (f >= 0.f) ? f : LRELU * f;
    o[j] = f2bf(f);
  }
  *(bf16x8*)(x + e) = o;
}

// ---------------------------------------------------------------- L6: tiny conv (M=256, K=8192), VALU. out[n][co*4 + p] fp32
__global__ __launch_bounds__(256) void conv_l6(const __hip_bfloat16* __restrict__ x5,
                                               const __hip_bfloat16* __restrict__ wf,
                                               float* __restrict__ x6) {
  int n = blockIdx.x;
  int co = threadIdx.x & 63;
  int p  = threadIdx.x >> 6;        // wave-uniform
  int ho = p >> 1, wo = p & 1;
  float acc = 0.f;
  const __hip_bfloat16* xb = x5 + (size_t)n * 16 * 512;
  #pragma unroll
  for (int kh = 0; kh < 4; ++kh) {
    int ih = 2 * ho - 1 + kh;
    if ((unsigned)ih >= 4u) continue;
    #pragma unroll
    for (int kw = 0; kw < 4; ++kw) {
      int iw = 2 * wo - 1 + kw;
      if ((unsigned)iw >= 4u) continue;
      const __hip_bfloat16* xr = xb + (ih * 4 + iw) * 512;
      const __hip_bfloat16* wr = wf + (size_t)((kh * 4 + kw) * 512) * 64 + co;
      for (int ci = 0; ci < 512; ++ci)
        acc = fmaf(bf2f(*(const short*)&xr[ci]), bf2f(*(const short*)&wr[(size_t)ci * 64]), acc);
    }
  }
  x6[n * 256 + co * 4 + p] = acc;
}

// ---------------------------------------------------------------- tail (proven round 1)
__global__ __launch_bounds__(256) void ms_kernel(const float* __restrict__ x6, const float* __restrict__ T,
                                                 float* __restrict__ Ms, float* __restrict__ out) {
  const int n = blockIdx.x;
  const int tid = threadIdx.x;
  __shared__ float fs[256];
  const float f = x6[(size_t)n * 256 + tid];
  fs[tid] = f;
  out[(size_t)n * 320 + tid] = f;
  __syncthreads();
  float acc[16];
  #pragma unroll
  for (int k = 0; k < 16; ++k) acc[k] = 0.f;
  for (int a = 0; a < 256; ++a) {
    const float fa = fs[a];
    const float* __restrict__ Trow = T + (size_t)a * 4096 + tid;
    #pragma unroll
    for (int k = 0; k < 16; ++k) acc[k] = fmaf(fa, Trow[(size_t)k * 256], acc[k]);
  }
  #pragma unroll
  for (int k = 0; k < 16; ++k) Ms[(size_t)n * 4096 + tid + (size_t)k * 256] = acc[k];
}

__global__ __launch_bounds__(256) void mbd_kernel(const float* __restrict__ Ms, float* __restrict__ out) {
  const int b = blockIdx.x;
  const int tid = threadIdx.x;
  __shared__ float Mb[64][65];
  for (int idx = tid; idx < 4096; idx += 256) {
    const int i = idx >> 6, c = idx & 63;
    Mb[i][c] = Ms[(size_t)i * 4096 + b * 64 + c];
  }
  __syncthreads();
  const int i = tid >> 2, jj = tid & 3;
  float ssum = 0.f;
  for (int j = jj; j < 64; j += 4) {
    float d = 0.f;
    #pragma unroll
    for (int c = 0; c < 64; ++c) d += fabsf(Mb[i][c] - Mb[j][c]);
    ssum += expf(-d);
  }
  ssum += __shfl_xor(ssum, 1, 64);
  ssum += __shfl_xor(ssum, 2, 64);
  if (jj == 0) out[(size_t)i * 320 + 256 + b] = ssum;
}

// ---------------------------------------------------------------- launch
extern "C" void kernel_launch(void* const* d_in, const int* in_sizes, int n_in,
                              void* d_out, int out_size, void* d_ws, size_t ws_size,
                              hipStream_t stream) {
  const float* image = (const float*)d_in[0];
  const float* W[6] = {(const float*)d_in[1], (const float*)d_in[3], (const float*)d_in[5],
                       (const float*)d_in[7], (const float*)d_in[9], (const float*)d_in[11]};
  const float* U[6] = {(const float*)d_in[2], (const float*)d_in[4], (const float*)d_in[6],
                       (const float*)d_in[8], (const float*)d_in[10], (const float*)d_in[12]};
  const float* G[4] = {(const float*)d_in[13], (const float*)d_in[15],
                       (const float*)d_in[17], (const float*)d_in[19]};
  const float* Bb[4] = {(const float*)d_in[14], (const float*)d_in[16],
                        (const float*)d_in[18], (const float*)d_in[20]};
  const float* T = (const float*)d_in[21];
  float* out = (float*)d_out;

  // ---- workspace layout
  float* f = (float*)d_ws;
  float* inv_sigma = f;                          // 16
  float* part      = f + 1024;                   // 65536 (2x64x512 max)
  float* sb        = f + 1024 + 65536;           // 1024
  float* x6        = f + 1024 + 65536 + 1024;    // 16384
  float* Ms        = f + 1024 + 65536 + 1024 + 16384; // 262144
  __hip_bfloat16* bfb = (__hip_bfloat16*)(f + 524288);
  const size_t REGION = 16777216 + 2048;         // elems + zero pad
  __hip_bfloat16* region0 = bfb;                 // a2col / x2 / x4
  __hip_bfloat16* region1 = region0 + REGION;    // x1 / x3 / x5
  __hip_bfloat16* wf1 = region1 + REGION;        // 4096
  __hip_bfloat16* wf2 = wf1 + 4096;              // 131072
  __hip_bfloat16* wf3 = wf2 + 131072;            // 524288
  __hip_bfloat16* wf4 = wf3 + 524288;            // 1048576
  __hip_bfloat16* wf5 = wf4 + 1048576;           // 2097152
  __hip_bfloat16* wf6 = wf5 + 2097152;           // 524288

  __hip_bfloat16* a2col = region0;
  __hip_bfloat16* x1 = region1;
  __hip_bfloat16* x2 = region0;
  __hip_bfloat16* x3 = region1;
  __hip_bfloat16* x4 = region0;
  __hip_bfloat16* x5 = region1;

  zero_pads<<<8, 256, 0, stream>>>(region0, region1);

  SNArgs sa;
  const int outc[6] = {64, 128, 256, 256, 512, 64};
  const int ink[6]  = {48, 1024, 2048, 4096, 4096, 8192};
  for (int l = 0; l < 6; ++l) { sa.w[l] = W[l]; sa.u[l] = U[l]; sa.outc[l] = outc[l]; sa.ink[l] = ink[l]; }
  sn_sigma_all<<<6, 256, 0, stream>>>(sa, inv_sigma);

  // weight prepacks (fold 1/sigma)
  prepack_w<<<16,    256, 0, stream>>>(W[0], inv_sigma + 0, wf1, 3,   64,  64,   48);
  prepack_w<<<512,   256, 0, stream>>>(W[1], inv_sigma + 1, wf2, 64,  128, 1024, 1024);
  prepack_w<<<2048,  256, 0, stream>>>(W[2], inv_sigma + 2, wf3, 128, 256, 2048, 2048);
  prepack_w<<<4096,  256, 0, stream>>>(W[3], inv_sigma + 3, wf4, 256, 256, 4096, 4096);
  prepack_w<<<8192,  256, 0, stream>>>(W[4], inv_sigma + 4, wf5, 256, 512, 4096, 4096);
  prepack_w6<<<2048, 256, 0, stream>>>(W[5], inv_sigma + 5, wf6);

  im2col_l1<<<1024, 256, 0, stream>>>(image, a2col);

  // L1: [262144 x 64] @ [64 x 64], fused lrelu
  conv_mfma<64, 64, 1, 1, 1, 4, true><<<dim3(2048, 1), 256, 0, stream>>>(a2col, wf1, x1);

  auto bn = [&](__hip_bfloat16* x, int bi, int M, int C) {
    bn_stats_a<<<dim3(64, C / 64), 256, 0, stream>>>(x, part, M, C);
    bn_stats_b<<<C / 64, 64, 0, stream>>>(part, G[bi], Bb[bi], sb, M, C);
    int nvec = M * C / 8;
    bn_apply<<<(nvec + 255) / 256, 256, 0, stream>>>(x, sb, C, nvec);
  };

  // L2: 64ch 64x64 -> 128ch 32x32
  conv_mfma<64, 128, 64, 32, 4, 4, false><<<dim3(512, 2), 256, 0, stream>>>(x1, wf2, x2);
  bn(x2, 0, 65536, 128);
  // L3: 128ch 32x32 -> 256ch 16x16
  conv_mfma<128, 256, 32, 16, 4, 4, false><<<dim3(128, 4), 256, 0, stream>>>(x2, wf3, x3);
  bn(x3, 1, 16384, 256);
  // L4: 256ch 16x16 -> 256ch 8x8
  conv_mfma<256, 256, 16, 8, 4, 2, false><<<dim3(64, 4), 256, 0, stream>>>(x3, wf4, x4);
  bn(x4, 2, 4096, 256);
  // L5: 256ch 8x8 -> 512ch 4x4
  conv_mfma<256, 512, 8, 4, 4, 1, false><<<dim3(32, 8), 256, 0, stream>>>(x4, wf5, x5);
  bn(x5, 3, 1024, 512);
  // L6: 512ch 4x4 -> 64ch 2x2 (fp32 out, NCHW-flat order for the tail)
  conv_l6<<<64, 256, 0, stream>>>(x5, wf6, x6);

  ms_kernel<<<64, 256, 0, stream>>>(x6, T, Ms, out);
  mbd_kernel<<<64, 256, 0, stream>>>(Ms, out);
}

// Round 3
// 897.116 us; speedup vs baseline: 8.9100x; 1.7788x over previous
//
#include <hip/hip_runtime.h>
#include <hip/hip_bf16.h>
#include <math.h>

#define LRELU 0.2f
#define BN_EPS 1e-5f
#define SN_EPS 1e-12f

typedef __attribute__((ext_vector_type(4))) float f32x4;
typedef __attribute__((ext_vector_type(8))) short bf16x8;

__device__ inline float bf2f(short s) {
  union { unsigned u; float f; } c; c.u = ((unsigned)(unsigned short)s) << 16; return c.f;
}
__device__ inline short f2bf(float f) {
  __hip_bfloat16 h = __float2bfloat16(f); return *(short*)&h;
}

// ---------------------------------------------------------------- reductions
__device__ inline float blockReduceSum256(float v, volatile float* red) {
  #pragma unroll
  for (int o = 32; o > 0; o >>= 1) v += __shfl_down(v, o, 64);
  const int tid = threadIdx.x;
  __syncthreads();
  if ((tid & 63) == 0) red[tid >> 6] = v;
  __syncthreads();
  return red[0] + red[1] + red[2] + red[3];
}

// ---------------------------------------------------------------- spectral norm, parallel 4-stage chain
struct SNArgs {
  const float* w[6];
  const float* u[6];
  int outc[6];
  int ink[6];
};

// stage 1: vraw[l][j] = sum_i W[i,j]*u[i]; block partial of ||vraw||^2
__global__ __launch_bounds__(256) void sn_v(SNArgs args, float* __restrict__ vbuf,
                                            float* __restrict__ pA) {
  const int l = blockIdx.y;
  const int in_k = args.ink[l], out_c = args.outc[l];
  const int tid = threadIdx.x;
  const int j = blockIdx.x * 256 + tid;
  __shared__ float uS[512];
  __shared__ float red[4];
  for (int i = tid; i < out_c; i += 256) uS[i] = args.u[l][i];
  __syncthreads();
  float t = 0.f;
  if (j < in_k) {
    const float* __restrict__ w = args.w[l];
    #pragma unroll 4
    for (int i = 0; i < out_c; ++i) t = fmaf(w[(size_t)i * in_k + j], uS[i], t);
    vbuf[l * 8192 + j] = t;
  }
  const float bs = blockReduceSum256((j < in_k) ? t * t : 0.f, red);
  if (tid == 0) pA[l * 32 + blockIdx.x] = bs;
}

// stage 2: rinv[l] = 1/(||v||+eps)   (fixed-order reduce -> deterministic)
__global__ __launch_bounds__(64) void sn_norm1(SNArgs args, const float* __restrict__ pA,
                                               float* __restrict__ rinv) {
  const int l = blockIdx.x;
  if (threadIdx.x != 0) return;
  const int nb = (args.ink[l] + 255) >> 8;
  float s = 0.f;
  for (int b = 0; b < nb; ++b) s += pA[l * 32 + b];
  rinv[l] = 1.f / (sqrtf(s) + SN_EPS);
}

// stage 3: t2_i = rinv * (W vraw)_i; block partial of ||t2||^2. one wave per row.
__global__ __launch_bounds__(256) void sn_t2(SNArgs args, const float* __restrict__ vbuf,
                                             const float* __restrict__ rinv,
                                             float* __restrict__ pB) {
  const int l = blockIdx.y;
  const int in_k = args.ink[l], out_c = args.outc[l];
  const int tid = threadIdx.x;
  const int lane = tid & 63, wv = tid >> 6;
  const float* __restrict__ W = args.w[l];
  const float* __restrict__ v = vbuf + l * 8192;
  const float r = rinv[l];
  float sqacc = 0.f;
  for (int row = blockIdx.x * 4 + wv; row < out_c; row += 128) {
    float t = 0.f;
    const float* __restrict__ wr = W + (size_t)row * in_k;
    for (int j = lane; j < in_k; j += 64) t = fmaf(wr[j], v[j], t);
    #pragma unroll
    for (int o = 32; o > 0; o >>= 1) t += __shfl_down(t, o, 64);
    if (lane == 0) { t *= r; sqacc = fmaf(t, t, sqacc); }
  }
  __shared__ float red[4];
  __syncthreads();
  if (lane == 0) red[wv] = sqacc;
  __syncthreads();
  if (tid == 0) pB[l * 32 + blockIdx.x] = red[0] + red[1] + red[2] + red[3];
}

// stage 4: sigma = ||t2||^2/(||t2||+eps); inv_sigma = 1/sigma
__global__ __launch_bounds__(64) void sn_norm2(const float* __restrict__ pB,
                                               float* __restrict__ inv_sigma) {
  const int l = blockIdx.x;
  if (threadIdx.x != 0) return;
  float s = 0.f;
  for (int b = 0; b < 32; ++b) s += pB[l * 32 + b];
  const float n2 = sqrtf(s);
  const float sigma = s / (n2 + SN_EPS);
  inv_sigma[l] = 1.f / sigma;
}

// ---------------------------------------------------------------- zero the OOB pad regions
__global__ __launch_bounds__(256) void zero_pads(__hip_bfloat16* r0, __hip_bfloat16* r1) {
  int t = blockIdx.x * 256 + threadIdx.x;
  if (t < 2048) {
    r0[16777216 + t] = __float2bfloat16(0.f);
    r1[16777216 + t] = __float2bfloat16(0.f);
  }
}

// ---------------------------------------------------------------- weight prepack into MFMA-fragment order
__global__ __launch_bounds__(256) void prepack_w(const float* __restrict__ w,
                                                 const float* __restrict__ invs,
                                                 __hip_bfloat16* __restrict__ dst,
                                                 int CINR, int COUT, int KPAD, int KREAL) {
  int e = blockIdx.x * 256 + threadIdx.x;
  if (e >= KPAD * COUT) return;
  int j = e & 7, lane = (e >> 3) & 63, frag = e >> 9;
  int nfrags = COUT >> 4;
  int ks = frag / nfrags, nf = frag - ks * nfrags;
  int k = ks * 32 + ((lane >> 4) << 3) + j;
  int co = (nf << 4) + (lane & 15);
  float val = 0.f;
  if (k < KREAL) {
    int khw = k / CINR, ci = k - khw * CINR;
    int kh = khw >> 2, kw = khw & 3;
    val = w[(((size_t)co * CINR + ci) * 4 + kh) * 4 + kw] * invs[0];
  }
  dst[e] = __float2bfloat16(val);
}

__global__ __launch_bounds__(256) void prepack_w6(const float* __restrict__ w,
                                                  const float* __restrict__ invs,
                                                  __hip_bfloat16* __restrict__ dst) {
  int e = blockIdx.x * 256 + threadIdx.x;   // 524288
  int k = e >> 6, co = e & 63;
  int khw = k >> 9, ci = k & 511;
  int kh = khw >> 2, kw = khw & 3;
  dst[e] = __float2bfloat16(w[(((size_t)co * 512 + ci) * 4 + kh) * 4 + kw] * invs[0]);
}

// ---------------------------------------------------------------- L1 im2col
__global__ __launch_bounds__(256) void im2col_l1(const float* __restrict__ img,
                                                 __hip_bfloat16* __restrict__ a2) {
  int m = blockIdx.x * 256 + threadIdx.x;      // 262144
  int n = m >> 12;
  int hw = m & 4095;
  int ho = hw >> 6, wo = hw & 63;
  int ihb = 2 * ho - 1, iwb = 2 * wo - 1;
  const float* ib = img + (size_t)n * 3 * 128 * 128;
  __hip_bfloat16* o = a2 + (size_t)m * 64;
  #pragma unroll
  for (int kh = 0; kh < 4; ++kh) {
    int ih = ihb + kh;
    bool vh = (unsigned)ih < 128u;
    #pragma unroll
    for (int kw = 0; kw < 4; ++kw) {
      int iw = iwb + kw;
      bool v = vh && ((unsigned)iw < 128u);
      int khw = kh * 4 + kw;
      #pragma unroll
      for (int ci = 0; ci < 3; ++ci) {
        float val = v ? ib[(size_t)ci * 16384 + ih * 128 + iw] : 0.f;
        o[khw * 3 + ci] = __float2bfloat16(val);
      }
    }
  }
  #pragma unroll
  for (int k = 48; k < 64; ++k) o[k] = __float2bfloat16(0.f);
}

// ---------------------------------------------------------------- MFMA implicit-GEMM conv
template<int CIN, int COUT, int HIN, int HOUT, int KH, int MF, bool FUSE>
__global__ __launch_bounds__(256) void conv_mfma(
    const __hip_bfloat16* __restrict__ x,
    const __hip_bfloat16* __restrict__ wf,
    __hip_bfloat16* __restrict__ out)
{
  constexpr int WIN = HIN, WO = HOUT;
  constexpr int KHW = KH * KH;
  constexpr int CB = CIN / 32;
  constexpr int PADOFF = 16777216;

  const int lane = threadIdx.x & 63;
  const int wid  = threadIdx.x >> 6;
  const int wm = wid >> 1, wn = wid & 1;
  const int mbase = blockIdx.x * (MF * 32) + wm * (MF * 16);
  const int cobase = blockIdx.y * 64 + wn * 32;

  int offm[MF], ihb[MF], iwb[MF];
  #pragma unroll
  for (int mf = 0; mf < MF; ++mf) {
    int m = mbase + mf * 16 + (lane & 15);
    if (KH == 1) {
      ihb[mf] = 0; iwb[mf] = 0; offm[mf] = m * CIN;
    } else {
      int n = m / (HOUT * WO);
      int hw = m - n * (HOUT * WO);
      int ho = hw / WO, wo = hw - ho * WO;
      ihb[mf] = 2 * ho - 1;
      iwb[mf] = 2 * wo - 1;
      offm[mf] = ((n * HIN + ihb[mf]) * WIN + iwb[mf]) * CIN;
    }
  }
  const int koff = (lane >> 4) << 3;
  const __hip_bfloat16* wfp = wf + ((size_t)((blockIdx.y * 4 + wn * 2) * 64 + lane)) * 8;

  f32x4 acc[MF][2];
  #pragma unroll
  for (int mf = 0; mf < MF; ++mf) {
    acc[mf][0] = (f32x4){0.f, 0.f, 0.f, 0.f};
    acc[mf][1] = (f32x4){0.f, 0.f, 0.f, 0.f};
  }

  #pragma unroll
  for (int khw = 0; khw < KHW; ++khw) {
    const int kh = khw >> 2, kw = khw & 3;
    const __hip_bfloat16* ap[MF];
    #pragma unroll
    for (int mf = 0; mf < MF; ++mf) {
      int off;
      if (KH == 1) {
        off = offm[mf] + koff;
      } else {
        int ih = ihb[mf] + kh, iw = iwb[mf] + kw;
        bool v = ((unsigned)ih < (unsigned)HIN) & ((unsigned)iw < (unsigned)WIN);
        off = v ? (offm[mf] + (kh * WIN + kw) * CIN + koff) : (PADOFF + koff);
      }
      ap[mf] = x + off;
    }
    #pragma unroll
    for (int cb = 0; cb < CB; ++cb) {
      const int ks = khw * CB + cb;
      bf16x8 a[MF], b[2];
      #pragma unroll
      for (int mf = 0; mf < MF; ++mf) a[mf] = *(const bf16x8*)(ap[mf] + cb * 32);
      #pragma unroll
      for (int nf = 0; nf < 2; ++nf)
        b[nf] = *(const bf16x8*)(wfp + (size_t)ks * (COUT * 32) + nf * 512);
      #pragma unroll
      for (int mf = 0; mf < MF; ++mf)
        #pragma unroll
        for (int nf = 0; nf < 2; ++nf)
          acc[mf][nf] = __builtin_amdgcn_mfma_f32_16x16x32_bf16(a[mf], b[nf], acc[mf][nf], 0, 0, 0);
    }
  }

  const int r0 = (lane >> 4) * 4;
  const int cw = cobase + (lane & 15);
  #pragma unroll
  for (int mf = 0; mf < MF; ++mf)
    #pragma unroll
    for (int nf = 0; nf < 2; ++nf)
      #pragma unroll
      for (int r = 0; r < 4; ++r) {
        float v = acc[mf][nf][r];
        if (FUSE) v = (v >= 0.f) ? v : LRELU * v;
        int m = mbase + mf * 16 + r0 + r;
        out[(size_t)m * COUT + (cw + nf * 16)] = __float2bfloat16(v);
      }
}

// ---------------------------------------------------------------- BN stats (deterministic 2-stage), NHWC bf16
__global__ __launch_bounds__(256) void bn_stats_a(const __hip_bfloat16* __restrict__ x,
                                                  float* __restrict__ part, int M, int C) {
  const int chunk = blockIdx.x;
  const int c = blockIdx.y * 64 + (threadIdx.x & 63);
  const int msub = threadIdx.x >> 6;
  const int MC = M >> 6;
  float s = 0.f, s2 = 0.f;
  for (int mi = msub; mi < MC; mi += 4) {
    int m = chunk * MC + mi;
    float v = bf2f(*(const short*)&x[(size_t)m * C + c]);
    s += v;
    s2 = fmaf(v, v, s2);
  }
  __shared__ float ls[256], ls2[256];
  ls[threadIdx.x] = s; ls2[threadIdx.x] = s2;
  __syncthreads();
  if (msub == 0) {
    int t = threadIdx.x;
    s  = ls[t]  + ls[t + 64]  + ls[t + 128]  + ls[t + 192];
    s2 = ls2[t] + ls2[t + 64] + ls2[t + 128] + ls2[t + 192];
    part[(size_t)chunk * C + c] = s;
    part[(size_t)(64 + chunk) * C + c] = s2;
  }
}

__global__ __launch_bounds__(64) void bn_stats_b(const float* __restrict__ part,
                                                 const float* __restrict__ g,
                                                 const float* __restrict__ b,
                                                 float* __restrict__ sb, int M, int C) {
  int c = blockIdx.x * 64 + threadIdx.x;
  float s = 0.f, s2 = 0.f;
  for (int ch = 0; ch < 64; ++ch) { s += part[(size_t)ch * C + c]; s2 += part[(size_t)(64 + ch) * C + c]; }
  float invM = 1.f / (float)M;
  float mean = s * invM;
  float var = s2 * invM - mean * mean;
  float scale = g[c] * rsqrtf(var + BN_EPS);
  sb[c] = scale;
  sb[C + c] = b[c] - mean * scale;
}

__global__ __launch_bounds__(256) void bn_apply(__hip_bfloat16* __restrict__ x,
                                                const float* __restrict__ sb,
                                                int C, int nvec) {
  int idx = blockIdx.x * 256 + threadIdx.x;
  if (idx >= nvec) return;
  size_t e = (size_t)idx * 8;
  int c0 = (int)(e % (size_t)C);
  bf16x8 v = *(bf16x8*)(x + e);
  bf16x8 o;
  #pragma unroll
  for (int j = 0; j < 8; ++j) {
    int c = c0 + j;
    float f = bf2f(v[j]);
    f = fmaf(f, sb[c], sb[C + c]);
    f = (f >= 0.f) ? f : LRELU * f;
    o[j] = f2bf(f);
  }
  *(bf16x8*)(x + e) = o;
}

// ---------------------------------------------------------------- L6: tiny conv (M=256, K=8192)
__global__ __launch_bounds__(256) void conv_l6(const __hip_bfloat16* __restrict__ x5,
                                               const __hip_bfloat16* __restrict__ wf,
                                               float* __restrict__ x6) {
  int n = blockIdx.x;
  int co = threadIdx.x & 63;
  int p  = threadIdx.x >> 6;
  int ho = p >> 1, wo = p & 1;
  float acc = 0.f;
  const __hip_bfloat16* xb = x5 + (size_t)n * 16 * 512;
  #pragma unroll
  for (int kh = 0; kh < 4; ++kh) {
    int ih = 2 * ho - 1 + kh;
    if ((unsigned)ih >= 4u) continue;
    #pragma unroll
    for (int kw = 0; kw < 4; ++kw) {
      int iw = 2 * wo - 1 + kw;
      if ((unsigned)iw >= 4u) continue;
      const __hip_bfloat16* xr = xb + (ih * 4 + iw) * 512;
      const __hip_bfloat16* wr = wf + (size_t)((kh * 4 + kw) * 512) * 64 + co;
      for (int ci = 0; ci < 512; ++ci)
        acc = fmaf(bf2f(*(const short*)&xr[ci]), bf2f(*(const short*)&wr[(size_t)ci * 64]), acc);
    }
  }
  x6[n * 256 + co * 4 + p] = acc;
}

// ---------------------------------------------------------------- tail
__global__ __launch_bounds__(256) void ms_kernel(const float* __restrict__ x6, const float* __restrict__ T,
                                                 float* __restrict__ Ms, float* __restrict__ out) {
  const int n = blockIdx.x;
  const int tid = threadIdx.x;
  __shared__ float fs[256];
  const float f = x6[(size_t)n * 256 + tid];
  fs[tid] = f;
  out[(size_t)n * 320 + tid] = f;
  __syncthreads();
  float acc[16];
  #pragma unroll
  for (int k = 0; k < 16; ++k) acc[k] = 0.f;
  for (int a = 0; a < 256; ++a) {
    const float fa = fs[a];
    const float* __restrict__ Trow = T + (size_t)a * 4096 + tid;
    #pragma unroll
    for (int k = 0; k < 16; ++k) acc[k] = fmaf(fa, Trow[(size_t)k * 256], acc[k]);
  }
  #pragma unroll
  for (int k = 0; k < 16; ++k) Ms[(size_t)n * 4096 + tid + (size_t)k * 256] = acc[k];
}

__global__ __launch_bounds__(256) void mbd_kernel(const float* __restrict__ Ms, float* __restrict__ out) {
  const int b = blockIdx.x;
  const int tid = threadIdx.x;
  __shared__ float Mb[64][65];
  for (int idx = tid; idx < 4096; idx += 256) {
    const int i = idx >> 6, c = idx & 63;
    Mb[i][c] = Ms[(size_t)i * 4096 + b * 64 + c];
  }
  __syncthreads();
  const int i = tid >> 2, jj = tid & 3;
  float ssum = 0.f;
  for (int j = jj; j < 64; j += 4) {
    float d = 0.f;
    #pragma unroll
    for (int c = 0; c < 64; ++c) d += fabsf(Mb[i][c] - Mb[j][c]);
    ssum += expf(-d);
  }
  ssum += __shfl_xor(ssum, 1, 64);
  ssum += __shfl_xor(ssum, 2, 64);
  if (jj == 0) out[(size_t)i * 320 + 256 + b] = ssum;
}

// ---------------------------------------------------------------- launch
extern "C" void kernel_launch(void* const* d_in, const int* in_sizes, int n_in,
                              void* d_out, int out_size, void* d_ws, size_t ws_size,
                              hipStream_t stream) {
  const float* image = (const float*)d_in[0];
  const float* W[6] = {(const float*)d_in[1], (const float*)d_in[3], (const float*)d_in[5],
                       (const float*)d_in[7], (const float*)d_in[9], (const float*)d_in[11]};
  const float* U[6] = {(const float*)d_in[2], (const float*)d_in[4], (const float*)d_in[6],
                       (const float*)d_in[8], (const float*)d_in[10], (const float*)d_in[12]};
  const float* G[4] = {(const float*)d_in[13], (const float*)d_in[15],
                       (const float*)d_in[17], (const float*)d_in[19]};
  const float* Bb[4] = {(const float*)d_in[14], (const float*)d_in[16],
                        (const float*)d_in[18], (const float*)d_in[20]};
  const float* T = (const float*)d_in[21];
  float* out = (float*)d_out;

  // ---- workspace layout (floats)
  float* f = (float*)d_ws;
  float* inv_sigma = f;                                // 16
  float* part      = f + 1024;                         // 65536
  float* sb        = f + 1024 + 65536;                 // 1024
  float* x6        = f + 1024 + 65536 + 1024;          // 16384
  float* Ms        = f + 1024 + 65536 + 1024 + 16384;  // 262144  (ends 346128)
  float* vbuf      = f + 360448;                       // 6*8192 = 49152
  float* pA        = f + 360448 + 49152;               // 192
  float* pB        = pA + 256;                         // 192
  float* rinv      = pB + 256;                         // 16
  __hip_bfloat16* bfb = (__hip_bfloat16*)(f + 524288);
  const size_t REGION = 16777216 + 2048;
  __hip_bfloat16* region0 = bfb;
  __hip_bfloat16* region1 = region0 + REGION;
  __hip_bfloat16* wf1 = region1 + REGION;
  __hip_bfloat16* wf2 = wf1 + 4096;
  __hip_bfloat16* wf3 = wf2 + 131072;
  __hip_bfloat16* wf4 = wf3 + 524288;
  __hip_bfloat16* wf5 = wf4 + 1048576;
  __hip_bfloat16* wf6 = wf5 + 2097152;

  __hip_bfloat16* a2col = region0;
  __hip_bfloat16* x1 = region1;
  __hip_bfloat16* x2 = region0;
  __hip_bfloat16* x3 = region1;
  __hip_bfloat16* x4 = region0;
  __hip_bfloat16* x5 = region1;

  zero_pads<<<8, 256, 0, stream>>>(region0, region1);

  SNArgs sa;
  const int outc[6] = {64, 128, 256, 256, 512, 64};
  const int ink[6]  = {48, 1024, 2048, 4096, 4096, 8192};
  for (int l = 0; l < 6; ++l) { sa.w[l] = W[l]; sa.u[l] = U[l]; sa.outc[l] = outc[l]; sa.ink[l] = ink[l]; }

  // spectral norm: parallel 4-stage chain (deterministic fixed-order reductions)
  sn_v<<<dim3(32, 6), 256, 0, stream>>>(sa, vbuf, pA);
  sn_norm1<<<6, 64, 0, stream>>>(sa, pA, rinv);
  sn_t2<<<dim3(32, 6), 256, 0, stream>>>(sa, vbuf, rinv, pB);
  sn_norm2<<<6, 64, 0, stream>>>(pB, inv_sigma);

  // weight prepacks (fold 1/sigma)
  prepack_w<<<16,    256, 0, stream>>>(W[0], inv_sigma + 0, wf1, 3,   64,  64,   48);
  prepack_w<<<512,   256, 0, stream>>>(W[1], inv_sigma + 1, wf2, 64,  128, 1024, 1024);
  prepack_w<<<2048,  256, 0, stream>>>(W[2], inv_sigma + 2, wf3, 128, 256, 2048, 2048);
  prepack_w<<<4096,  256, 0, stream>>>(W[3], inv_sigma + 3, wf4, 256, 256, 4096, 4096);
  prepack_w<<<8192,  256, 0, stream>>>(W[4], inv_sigma + 4, wf5, 256, 512, 4096, 4096);
  prepack_w6<<<2048, 256, 0, stream>>>(W[5], inv_sigma + 5, wf6);

  im2col_l1<<<1024, 256, 0, stream>>>(image, a2col);

  conv_mfma<64, 64, 1, 1, 1, 4, true><<<dim3(2048, 1), 256, 0, stream>>>(a2col, wf1, x1);

  auto bn = [&](__hip_bfloat16* x, int bi, int M, int C) {
    bn_stats_a<<<dim3(64, C / 64), 256, 0, stream>>>(x, part, M, C);
    bn_stats_b<<<C / 64, 64, 0, stream>>>(part, G[bi], Bb[bi], sb, M, C);
    int nvec = M * C / 8;
    bn_apply<<<(nvec + 255) / 256, 256, 0, stream>>>(x, sb, C, nvec);
  };

  conv_mfma<64, 128, 64, 32, 4, 4, false><<<dim3(512, 2), 256, 0, stream>>>(x1, wf2, x2);
  bn(x2, 0, 65536, 128);
  conv_mfma<128, 256, 32, 16, 4, 4, false><<<dim3(128, 4), 256, 0, stream>>>(x2, wf3, x3);
  bn(x3, 1, 16384, 256);
  conv_mfma<256, 256, 16, 8, 4, 2, false><<<dim3(64, 4), 256, 0, stream>>>(x3, wf4, x4);
  bn(x4, 2, 4096, 256);
  conv_mfma<256, 512, 8, 4, 4, 1, false><<<dim3(32, 8), 256, 0, stream>>>(x4, wf5, x5);
  bn(x5, 3, 1024, 512);
  conv_l6<<<64, 256, 0, stream>>>(x5, wf6, x6);

  ms_kernel<<<64, 256, 0, stream>>>(x6, T, Ms, out);
  mbd_kernel<<<64, 256, 0, stream>>>(Ms, out);
}

// Round 4
// 761.427 us; speedup vs baseline: 10.4978x; 1.1782x over previous
//
#include <hip/hip_runtime.h>
#include <hip/hip_bf16.h>
#include <math.h>

#define LRELU 0.2f
#define BN_EPS 1e-5f
#define SN_EPS 1e-12f

typedef __attribute__((ext_vector_type(4))) float f32x4;
typedef __attribute__((ext_vector_type(8))) short bf16x8;

__device__ inline float bf2f(short s) {
  union { unsigned u; float f; } c; c.u = ((unsigned)(unsigned short)s) << 16; return c.f;
}
__device__ inline short f2bf(float f) {
  __hip_bfloat16 h = __float2bfloat16(f); return *(short*)&h;
}

// ---------------------------------------------------------------- reductions
__device__ inline float blockReduceSum256(float v, volatile float* red) {
  #pragma unroll
  for (int o = 32; o > 0; o >>= 1) v += __shfl_down(v, o, 64);
  const int tid = threadIdx.x;
  __syncthreads();
  if ((tid & 63) == 0) red[tid >> 6] = v;
  __syncthreads();
  return red[0] + red[1] + red[2] + red[3];
}

// ---------------------------------------------------------------- spectral norm, parallel 4-stage chain
struct SNArgs {
  const float* w[6];
  const float* u[6];
  int outc[6];
  int ink[6];
};

__global__ __launch_bounds__(256) void sn_v(SNArgs args, float* __restrict__ vbuf,
                                            float* __restrict__ pA) {
  const int l = blockIdx.y;
  const int in_k = args.ink[l], out_c = args.outc[l];
  const int tid = threadIdx.x;
  const int j = blockIdx.x * 256 + tid;
  __shared__ float uS[512];
  __shared__ float red[4];
  for (int i = tid; i < out_c; i += 256) uS[i] = args.u[l][i];
  __syncthreads();
  float t = 0.f;
  if (j < in_k) {
    const float* __restrict__ w = args.w[l];
    #pragma unroll 4
    for (int i = 0; i < out_c; ++i) t = fmaf(w[(size_t)i * in_k + j], uS[i], t);
    vbuf[l * 8192 + j] = t;
  }
  const float bs = blockReduceSum256((j < in_k) ? t * t : 0.f, red);
  if (tid == 0) pA[l * 32 + blockIdx.x] = bs;
}

__global__ __launch_bounds__(64) void sn_norm1(SNArgs args, const float* __restrict__ pA,
                                               float* __restrict__ rinv) {
  const int l = blockIdx.x;
  if (threadIdx.x != 0) return;
  const int nb = (args.ink[l] + 255) >> 8;
  float s = 0.f;
  for (int b = 0; b < nb; ++b) s += pA[l * 32 + b];
  rinv[l] = 1.f / (sqrtf(s) + SN_EPS);
}

__global__ __launch_bounds__(256) void sn_t2(SNArgs args, const float* __restrict__ vbuf,
                                             const float* __restrict__ rinv,
                                             float* __restrict__ pB) {
  const int l = blockIdx.y;
  const int in_k = args.ink[l], out_c = args.outc[l];
  const int tid = threadIdx.x;
  const int lane = tid & 63, wv = tid >> 6;
  const float* __restrict__ W = args.w[l];
  const float* __restrict__ v = vbuf + l * 8192;
  const float r = rinv[l];
  float sqacc = 0.f;
  for (int row = blockIdx.x * 4 + wv; row < out_c; row += 128) {
    float t = 0.f;
    const float* __restrict__ wr = W + (size_t)row * in_k;
    for (int j = lane; j < in_k; j += 64) t = fmaf(wr[j], v[j], t);
    #pragma unroll
    for (int o = 32; o > 0; o >>= 1) t += __shfl_down(t, o, 64);
    if (lane == 0) { t *= r; sqacc = fmaf(t, t, sqacc); }
  }
  __shared__ float red[4];
  __syncthreads();
  if (lane == 0) red[wv] = sqacc;
  __syncthreads();
  if (tid == 0) pB[l * 32 + blockIdx.x] = red[0] + red[1] + red[2] + red[3];
}

__global__ __launch_bounds__(64) void sn_norm2(const float* __restrict__ pB,
                                               float* __restrict__ inv_sigma) {
  const int l = blockIdx.x;
  if (threadIdx.x != 0) return;
  float s = 0.f;
  for (int b = 0; b < 32; ++b) s += pB[l * 32 + b];
  const float n2 = sqrtf(s);
  const float sigma = s / (n2 + SN_EPS);
  inv_sigma[l] = 1.f / sigma;
}

// ---------------------------------------------------------------- zero the OOB pad regions
__global__ __launch_bounds__(256) void zero_pads(__hip_bfloat16* r0, __hip_bfloat16* r1) {
  int t = blockIdx.x * 256 + threadIdx.x;
  if (t < 2048) {
    r0[16777216 + t] = __float2bfloat16(0.f);
    r1[16777216 + t] = __float2bfloat16(0.f);
  }
}

// ---------------------------------------------------------------- weight prepack into MFMA-fragment order
__global__ __launch_bounds__(256) void prepack_w(const float* __restrict__ w,
                                                 const float* __restrict__ invs,
                                                 __hip_bfloat16* __restrict__ dst,
                                                 int CINR, int COUT, int KPAD, int KREAL) {
  int e = blockIdx.x * 256 + threadIdx.x;
  if (e >= KPAD * COUT) return;
  int j = e & 7, lane = (e >> 3) & 63, frag = e >> 9;
  int nfrags = COUT >> 4;
  int ks = frag / nfrags, nf = frag - ks * nfrags;
  int k = ks * 32 + ((lane >> 4) << 3) + j;
  int co = (nf << 4) + (lane & 15);
  float val = 0.f;
  if (k < KREAL) {
    int khw = k / CINR, ci = k - khw * CINR;
    int kh = khw >> 2, kw = khw & 3;
    val = w[(((size_t)co * CINR + ci) * 4 + kh) * 4 + kw] * invs[0];
  }
  dst[e] = __float2bfloat16(val);
}

// ---------------------------------------------------------------- L1 im2col
__global__ __launch_bounds__(256) void im2col_l1(const float* __restrict__ img,
                                                 __hip_bfloat16* __restrict__ a2) {
  int m = blockIdx.x * 256 + threadIdx.x;      // 262144
  int n = m >> 12;
  int hw = m & 4095;
  int ho = hw >> 6, wo = hw & 63;
  int ihb = 2 * ho - 1, iwb = 2 * wo - 1;
  const float* ib = img + (size_t)n * 3 * 128 * 128;
  __hip_bfloat16* o = a2 + (size_t)m * 64;
  #pragma unroll
  for (int kh = 0; kh < 4; ++kh) {
    int ih = ihb + kh;
    bool vh = (unsigned)ih < 128u;
    #pragma unroll
    for (int kw = 0; kw < 4; ++kw) {
      int iw = iwb + kw;
      bool v = vh && ((unsigned)iw < 128u);
      int khw = kh * 4 + kw;
      #pragma unroll
      for (int ci = 0; ci < 3; ++ci) {
        float val = v ? ib[(size_t)ci * 16384 + ih * 128 + iw] : 0.f;
        o[khw * 3 + ci] = __float2bfloat16(val);
      }
    }
  }
  #pragma unroll
  for (int k = 48; k < 64; ++k) o[k] = __float2bfloat16(0.f);
}

// ---------------------------------------------------------------- MFMA implicit-GEMM conv
template<int CIN, int COUT, int HIN, int HOUT, int KH, int MF, bool FUSE>
__global__ __launch_bounds__(256) void conv_mfma(
    const __hip_bfloat16* __restrict__ x,
    const __hip_bfloat16* __restrict__ wf,
    __hip_bfloat16* __restrict__ out)
{
  constexpr int WIN = HIN, WO = HOUT;
  constexpr int KHW = KH * KH;
  constexpr int CB = CIN / 32;
  constexpr int PADOFF = 16777216;

  const int lane = threadIdx.x & 63;
  const int wid  = threadIdx.x >> 6;
  const int wm = wid >> 1, wn = wid & 1;
  const int mbase = blockIdx.x * (MF * 32) + wm * (MF * 16);
  const int cobase = blockIdx.y * 64 + wn * 32;

  int offm[MF], ihb[MF], iwb[MF];
  #pragma unroll
  for (int mf = 0; mf < MF; ++mf) {
    int m = mbase + mf * 16 + (lane & 15);
    if (KH == 1) {
      ihb[mf] = 0; iwb[mf] = 0; offm[mf] = m * CIN;
    } else {
      int n = m / (HOUT * WO);
      int hw = m - n * (HOUT * WO);
      int ho = hw / WO, wo = hw - ho * WO;
      ihb[mf] = 2 * ho - 1;
      iwb[mf] = 2 * wo - 1;
      offm[mf] = ((n * HIN + ihb[mf]) * WIN + iwb[mf]) * CIN;
    }
  }
  const int koff = (lane >> 4) << 3;
  const __hip_bfloat16* wfp = wf + ((size_t)((blockIdx.y * 4 + wn * 2) * 64 + lane)) * 8;

  f32x4 acc[MF][2];
  #pragma unroll
  for (int mf = 0; mf < MF; ++mf) {
    acc[mf][0] = (f32x4){0.f, 0.f, 0.f, 0.f};
    acc[mf][1] = (f32x4){0.f, 0.f, 0.f, 0.f};
  }

  #pragma unroll
  for (int khw = 0; khw < KHW; ++khw) {
    const int kh = khw >> 2, kw = khw & 3;
    const __hip_bfloat16* ap[MF];
    #pragma unroll
    for (int mf = 0; mf < MF; ++mf) {
      int off;
      if (KH == 1) {
        off = offm[mf] + koff;
      } else {
        int ih = ihb[mf] + kh, iw = iwb[mf] + kw;
        bool v = ((unsigned)ih < (unsigned)HIN) & ((unsigned)iw < (unsigned)WIN);
        off = v ? (offm[mf] + (kh * WIN + kw) * CIN + koff) : (PADOFF + koff);
      }
      ap[mf] = x + off;
    }
    #pragma unroll
    for (int cb = 0; cb < CB; ++cb) {
      const int ks = khw * CB + cb;
      bf16x8 a[MF], b[2];
      #pragma unroll
      for (int mf = 0; mf < MF; ++mf) a[mf] = *(const bf16x8*)(ap[mf] + cb * 32);
      #pragma unroll
      for (int nf = 0; nf < 2; ++nf)
        b[nf] = *(const bf16x8*)(wfp + (size_t)ks * (COUT * 32) + nf * 512);
      #pragma unroll
      for (int mf = 0; mf < MF; ++mf)
        #pragma unroll
        for (int nf = 0; nf < 2; ++nf)
          acc[mf][nf] = __builtin_amdgcn_mfma_f32_16x16x32_bf16(a[mf], b[nf], acc[mf][nf], 0, 0, 0);
    }
  }

  const int r0 = (lane >> 4) * 4;
  const int cw = cobase + (lane & 15);
  #pragma unroll
  for (int mf = 0; mf < MF; ++mf)
    #pragma unroll
    for (int nf = 0; nf < 2; ++nf)
      #pragma unroll
      for (int r = 0; r < 4; ++r) {
        float v = acc[mf][nf][r];
        if (FUSE) v = (v >= 0.f) ? v : LRELU * v;
        int m = mbase + mf * 16 + r0 + r;
        out[(size_t)m * COUT + (cw + nf * 16)] = __float2bfloat16(v);
      }
}

// ---------------------------------------------------------------- L6 MFMA conv: x5 NHWC [64,4,4,512] -> x6 fp32 [n*256 + co*4 + p]
__global__ __launch_bounds__(256) void conv_l6_mfma(
    const __hip_bfloat16* __restrict__ x,
    const __hip_bfloat16* __restrict__ wf,
    float* __restrict__ x6)
{
  constexpr int CIN = 512, COUT = 64, HIN = 4, WO = 2;
  constexpr int CB = CIN / 32;
  constexpr int PADOFF = 16777216;

  const int lane = threadIdx.x & 63;
  const int wid  = threadIdx.x >> 6;
  const int wm = wid >> 1, wn = wid & 1;
  const int mbase = blockIdx.x * 32 + wm * 16;

  int m0 = mbase + (lane & 15);
  int n = m0 >> 2;
  int hw = m0 & 3;
  int ho = hw >> 1, wo = hw & 1;
  int ihb = 2 * ho - 1;
  int iwb = 2 * wo - 1;
  int offm = ((n * HIN + ihb) * HIN + iwb) * CIN;

  const int koff = (lane >> 4) << 3;
  const __hip_bfloat16* wfp = wf + ((size_t)((wn * 2) * 64 + lane)) * 8;

  f32x4 acc[2];
  acc[0] = (f32x4){0.f, 0.f, 0.f, 0.f};
  acc[1] = (f32x4){0.f, 0.f, 0.f, 0.f};

  #pragma unroll
  for (int khw = 0; khw < 16; ++khw) {
    const int kh = khw >> 2, kw = khw & 3;
    const int ih = ihb + kh, iw = iwb + kw;
    const bool v = ((unsigned)ih < (unsigned)HIN) & ((unsigned)iw < (unsigned)HIN);
    const int off = v ? (offm + (kh * HIN + kw) * CIN + koff) : (PADOFF + koff);
    const __hip_bfloat16* ap = x + off;
    #pragma unroll
    for (int cb = 0; cb < CB; ++cb) {
      const int ks = khw * CB + cb;
      bf16x8 a = *(const bf16x8*)(ap + cb * 32);
      bf16x8 b0 = *(const bf16x8*)(wfp + (size_t)ks * (COUT * 32));
      bf16x8 b1 = *(const bf16x8*)(wfp + (size_t)ks * (COUT * 32) + 512);
      acc[0] = __builtin_amdgcn_mfma_f32_16x16x32_bf16(a, b0, acc[0], 0, 0, 0);
      acc[1] = __builtin_amdgcn_mfma_f32_16x16x32_bf16(a, b1, acc[1], 0, 0, 0);
    }
  }

  const int r0 = (lane >> 4) * 4;
  const int cw = wn * 32 + (lane & 15);
  #pragma unroll
  for (int nf = 0; nf < 2; ++nf)
    #pragma unroll
    for (int r = 0; r < 4; ++r) {
      int m = mbase + r0 + r;
      int nn = m >> 2, p = m & 3;
      x6[(size_t)nn * 256 + (cw + nf * 16) * 4 + p] = acc[nf][r];
    }
}

// ---------------------------------------------------------------- BN stats (deterministic 2-stage), NHWC bf16
__global__ __launch_bounds__(256) void bn_stats_a(const __hip_bfloat16* __restrict__ x,
                                                  float* __restrict__ part, int M, int C) {
  const int chunk = blockIdx.x;
  const int c = blockIdx.y * 64 + (threadIdx.x & 63);
  const int msub = threadIdx.x >> 6;
  const int MC = M >> 6;
  float s = 0.f, s2 = 0.f;
  for (int mi = msub; mi < MC; mi += 4) {
    int m = chunk * MC + mi;
    float v = bf2f(*(const short*)&x[(size_t)m * C + c]);
    s += v;
    s2 = fmaf(v, v, s2);
  }
  __shared__ float ls[256], ls2[256];
  ls[threadIdx.x] = s; ls2[threadIdx.x] = s2;
  __syncthreads();
  if (msub == 0) {
    int t = threadIdx.x;
    s  = ls[t]  + ls[t + 64]  + ls[t + 128]  + ls[t + 192];
    s2 = ls2[t] + ls2[t + 64] + ls2[t + 128] + ls2[t + 192];
    part[(size_t)chunk * C + c] = s;
    part[(size_t)(64 + chunk) * C + c] = s2;
  }
}

__global__ __launch_bounds__(64) void bn_stats_b(const float* __restrict__ part,
                                                 const float* __restrict__ g,
                                                 const float* __restrict__ b,
                                                 float* __restrict__ sb, int M, int C) {
  int c = blockIdx.x * 64 + threadIdx.x;
  float s = 0.f, s2 = 0.f;
  for (int ch = 0; ch < 64; ++ch) { s += part[(size_t)ch * C + c]; s2 += part[(size_t)(64 + ch) * C + c]; }
  float invM = 1.f / (float)M;
  float mean = s * invM;
  float var = s2 * invM - mean * mean;
  float scale = g[c] * rsqrtf(var + BN_EPS);
  sb[c] = scale;
  sb[C + c] = b[c] - mean * scale;
}

__global__ __launch_bounds__(256) void bn_apply(__hip_bfloat16* __restrict__ x,
                                                const float* __restrict__ sb,
                                                int C, int nvec) {
  int idx = blockIdx.x * 256 + threadIdx.x;
  if (idx >= nvec) return;
  size_t e = (size_t)idx * 8;
  int c0 = (int)(e % (size_t)C);
  bf16x8 v = *(bf16x8*)(x + e);
  bf16x8 o;
  #pragma unroll
  for (int j = 0; j < 8; ++j) {
    int c = c0 + j;
    float f = bf2f(v[j]);
    f = fmaf(f, sb[c], sb[C + c]);
    f = (f >= 0.f) ? f : LRELU * f;
    o[j] = f2bf(f);
  }
  *(bf16x8*)(x + e) = o;
}

// ---------------------------------------------------------------- tail
__global__ __launch_bounds__(256) void ms_kernel(const float* __restrict__ x6, const float* __restrict__ T,
                                                 float* __restrict__ Ms, float* __restrict__ out) {
  const int n = blockIdx.x;
  const int tid = threadIdx.x;
  __shared__ float fs[256];
  const float f = x6[(size_t)n * 256 + tid];
  fs[tid] = f;
  out[(size_t)n * 320 + tid] = f;
  __syncthreads();
  float acc[16];
  #pragma unroll
  for (int k = 0; k < 16; ++k) acc[k] = 0.f;
  for (int a = 0; a < 256; ++a) {
    const float fa = fs[a];
    const float* __restrict__ Trow = T + (size_t)a * 4096 + tid;
    #pragma unroll
    for (int k = 0; k < 16; ++k) acc[k] = fmaf(fa, Trow[(size_t)k * 256], acc[k]);
  }
  #pragma unroll
  for (int k = 0; k < 16; ++k) Ms[(size_t)n * 4096 + tid + (size_t)k * 256] = acc[k];
}

__global__ __launch_bounds__(256) void mbd_kernel(const float* __restrict__ Ms, float* __restrict__ out) {
  const int b = blockIdx.x;
  const int tid = threadIdx.x;
  __shared__ float Mb[64][65];
  for (int idx = tid; idx < 4096; idx += 256) {
    const int i = idx >> 6, c = idx & 63;
    Mb[i][c] = Ms[(size_t)i * 4096 + b * 64 + c];
  }
  __syncthreads();
  const int i = tid >> 2, jj = tid & 3;
  float ssum = 0.f;
  for (int j = jj; j < 64; j += 4) {
    float d = 0.f;
    #pragma unroll
    for (int c = 0; c < 64; ++c) d += fabsf(Mb[i][c] - Mb[j][c]);
    ssum += expf(-d);
  }
  ssum += __shfl_xor(ssum, 1, 64);
  ssum += __shfl_xor(ssum, 2, 64);
  if (jj == 0) out[(size_t)i * 320 + 256 + b] = ssum;
}

// ---------------------------------------------------------------- launch
extern "C" void kernel_launch(void* const* d_in, const int* in_sizes, int n_in,
                              void* d_out, int out_size, void* d_ws, size_t ws_size,
                              hipStream_t stream) {
  const float* image = (const float*)d_in[0];
  const float* W[6] = {(const float*)d_in[1], (const float*)d_in[3], (const float*)d_in[5],
                       (const float*)d_in[7], (const float*)d_in[9], (const float*)d_in[11]};
  const float* U[6] = {(const float*)d_in[2], (const float*)d_in[4], (const float*)d_in[6],
                       (const float*)d_in[8], (const float*)d_in[10], (const float*)d_in[12]};
  const float* G[4] = {(const float*)d_in[13], (const float*)d_in[15],
                       (const float*)d_in[17], (const float*)d_in[19]};
  const float* Bb[4] = {(const float*)d_in[14], (const float*)d_in[16],
                        (const float*)d_in[18], (const float*)d_in[20]};
  const float* T = (const float*)d_in[21];
  float* out = (float*)d_out;

  // ---- workspace layout (floats)
  float* f = (float*)d_ws;
  float* inv_sigma = f;                                // 16
  float* part      = f + 1024;                         // 65536
  float* sb        = f + 1024 + 65536;                 // 1024
  float* x6        = f + 1024 + 65536 + 1024;          // 16384
  float* Ms        = f + 1024 + 65536 + 1024 + 16384;  // 262144
  float* vbuf      = f + 360448;                       // 49152
  float* pA        = f + 360448 + 49152;               // 192
  float* pB        = pA + 256;                         // 192
  float* rinv      = pB + 256;                         // 16
  __hip_bfloat16* bfb = (__hip_bfloat16*)(f + 524288);
  const size_t REGION = 16777216 + 2048;
  __hip_bfloat16* region0 = bfb;
  __hip_bfloat16* region1 = region0 + REGION;
  __hip_bfloat16* wf1 = region1 + REGION;
  __hip_bfloat16* wf2 = wf1 + 4096;
  __hip_bfloat16* wf3 = wf2 + 131072;
  __hip_bfloat16* wf4 = wf3 + 524288;
  __hip_bfloat16* wf5 = wf4 + 1048576;
  __hip_bfloat16* wf6 = wf5 + 2097152;

  __hip_bfloat16* a2col = region0;
  __hip_bfloat16* x1 = region1;
  __hip_bfloat16* x2 = region0;
  __hip_bfloat16* x3 = region1;
  __hip_bfloat16* x4 = region0;
  __hip_bfloat16* x5 = region1;

  zero_pads<<<8, 256, 0, stream>>>(region0, region1);

  SNArgs sa;
  const int outc[6] = {64, 128, 256, 256, 512, 64};
  const int ink[6]  = {48, 1024, 2048, 4096, 4096, 8192};
  for (int l = 0; l < 6; ++l) { sa.w[l] = W[l]; sa.u[l] = U[l]; sa.outc[l] = outc[l]; sa.ink[l] = ink[l]; }

  sn_v<<<dim3(32, 6), 256, 0, stream>>>(sa, vbuf, pA);
  sn_norm1<<<6, 64, 0, stream>>>(sa, pA, rinv);
  sn_t2<<<dim3(32, 6), 256, 0, stream>>>(sa, vbuf, rinv, pB);
  sn_norm2<<<6, 64, 0, stream>>>(pB, inv_sigma);

  prepack_w<<<16,    256, 0, stream>>>(W[0], inv_sigma + 0, wf1, 3,   64,  64,   48);
  prepack_w<<<512,   256, 0, stream>>>(W[1], inv_sigma + 1, wf2, 64,  128, 1024, 1024);
  prepack_w<<<2048,  256, 0, stream>>>(W[2], inv_sigma + 2, wf3, 128, 256, 2048, 2048);
  prepack_w<<<4096,  256, 0, stream>>>(W[3], inv_sigma + 3, wf4, 256, 256, 4096, 4096);
  prepack_w<<<8192,  256, 0, stream>>>(W[4], inv_sigma + 4, wf5, 256, 512, 4096, 4096);
  prepack_w<<<2048,  256, 0, stream>>>(W[5], inv_sigma + 5, wf6, 512, 64,  8192, 8192);

  im2col_l1<<<1024, 256, 0, stream>>>(image, a2col);

  conv_mfma<64, 64, 1, 1, 1, 4, true><<<dim3(2048, 1), 256, 0, stream>>>(a2col, wf1, x1);

  auto bn = [&](__hip_bfloat16* x, int bi, int M, int C) {
    bn_stats_a<<<dim3(64, C / 64), 256, 0, stream>>>(x, part, M, C);
    bn_stats_b<<<C / 64, 64, 0, stream>>>(part, G[bi], Bb[bi], sb, M, C);
    int nvec = M * C / 8;
    bn_apply<<<(nvec + 255) / 256, 256, 0, stream>>>(x, sb, C, nvec);
  };

  conv_mfma<64, 128, 64, 32, 4, 4, false><<<dim3(512, 2), 256, 0, stream>>>(x1, wf2, x2);
  bn(x2, 0, 65536, 128);
  conv_mfma<128, 256, 32, 16, 4, 4, false><<<dim3(128, 4), 256, 0, stream>>>(x2, wf3, x3);
  bn(x3, 1, 16384, 256);
  conv_mfma<256, 256, 16, 8, 4, 2, false><<<dim3(64, 4), 256, 0, stream>>>(x3, wf4, x4);
  bn(x4, 2, 4096, 256);
  conv_mfma<256, 512, 8, 4, 4, 1, false><<<dim3(32, 8), 256, 0, stream>>>(x4, wf5, x5);
  bn(x5, 3, 1024, 512);
  conv_l6_mfma<<<8, 256, 0, stream>>>(x5, wf6, x6);

  ms_kernel<<<64, 256, 0, stream>>>(x6, T, Ms, out);
  mbd_kernel<<<64, 256, 0, stream>>>(Ms, out);
}

// Round 5
// 654.844 us; speedup vs baseline: 12.2064x; 1.1628x over previous
//
#include <hip/hip_runtime.h>
#include <hip/hip_bf16.h>
#include <math.h>

#define LRELU 0.2f
#define BN_EPS 1e-5f
#define SN_EPS 1e-12f

typedef __attribute__((ext_vector_type(4))) float f32x4;
typedef __attribute__((ext_vector_type(8))) short bf16x8;

__device__ inline float bf2f(short s) {
  union { unsigned u; float f; } c; c.u = ((unsigned)(unsigned short)s) << 16; return c.f;
}
__device__ inline short f2bf(float f) {
  __hip_bfloat16 h = __float2bfloat16(f); return *(short*)&h;
}

// ---------------------------------------------------------------- reductions
__device__ inline float blockReduceSum256(float v, volatile float* red) {
  #pragma unroll
  for (int o = 32; o > 0; o >>= 1) v += __shfl_down(v, o, 64);
  const int tid = threadIdx.x;
  __syncthreads();
  if ((tid & 63) == 0) red[tid >> 6] = v;
  __syncthreads();
  return red[0] + red[1] + red[2] + red[3];
}

// ---------------------------------------------------------------- spectral norm, parallel 4-stage chain
struct SNArgs {
  const float* w[6];
  const float* u[6];
  int outc[6];
  int ink[6];
};

__global__ __launch_bounds__(256) void sn_v(SNArgs args, float* __restrict__ vbuf,
                                            float* __restrict__ pA) {
  const int l = blockIdx.y;
  const int in_k = args.ink[l], out_c = args.outc[l];
  const int tid = threadIdx.x;
  const int j = blockIdx.x * 256 + tid;
  __shared__ float uS[512];
  __shared__ float red[4];
  for (int i = tid; i < out_c; i += 256) uS[i] = args.u[l][i];
  __syncthreads();
  float t = 0.f;
  if (j < in_k) {
    const float* __restrict__ w = args.w[l];
    #pragma unroll 4
    for (int i = 0; i < out_c; ++i) t = fmaf(w[(size_t)i * in_k + j], uS[i], t);
    vbuf[l * 8192 + j] = t;
  }
  const float bs = blockReduceSum256((j < in_k) ? t * t : 0.f, red);
  if (tid == 0) pA[l * 32 + blockIdx.x] = bs;
}

__global__ __launch_bounds__(64) void sn_norm1(SNArgs args, const float* __restrict__ pA,
                                               float* __restrict__ rinv) {
  const int l = blockIdx.x;
  if (threadIdx.x != 0) return;
  const int nb = (args.ink[l] + 255) >> 8;
  float s = 0.f;
  for (int b = 0; b < nb; ++b) s += pA[l * 32 + b];
  rinv[l] = 1.f / (sqrtf(s) + SN_EPS);
}

__global__ __launch_bounds__(256) void sn_t2(SNArgs args, const float* __restrict__ vbuf,
                                             const float* __restrict__ rinv,
                                             float* __restrict__ pB) {
  const int l = blockIdx.y;
  const int in_k = args.ink[l], out_c = args.outc[l];
  const int tid = threadIdx.x;
  const int lane = tid & 63, wv = tid >> 6;
  const float* __restrict__ W = args.w[l];
  const float* __restrict__ v = vbuf + l * 8192;
  const float r = rinv[l];
  float sqacc = 0.f;
  for (int row = blockIdx.x * 4 + wv; row < out_c; row += 128) {
    float t = 0.f;
    const float* __restrict__ wr = W + (size_t)row * in_k;
    for (int j = lane; j < in_k; j += 64) t = fmaf(wr[j], v[j], t);
    #pragma unroll
    for (int o = 32; o > 0; o >>= 1) t += __shfl_down(t, o, 64);
    if (lane == 0) { t *= r; sqacc = fmaf(t, t, sqacc); }
  }
  __shared__ float red[4];
  __syncthreads();
  if (lane == 0) red[wv] = sqacc;
  __syncthreads();
  if (tid == 0) pB[l * 32 + blockIdx.x] = red[0] + red[1] + red[2] + red[3];
}

__global__ __launch_bounds__(64) void sn_norm2(const float* __restrict__ pB,
                                               float* __restrict__ inv_sigma) {
  const int l = blockIdx.x;
  if (threadIdx.x != 0) return;
  float s = 0.f;
  for (int b = 0; b < 32; ++b) s += pB[l * 32 + b];
  const float n2 = sqrtf(s);
  const float sigma = s / (n2 + SN_EPS);
  inv_sigma[l] = 1.f / sigma;
}

// ---------------------------------------------------------------- zero the OOB pad regions
__global__ __launch_bounds__(256) void zero_pads(__hip_bfloat16* r0, __hip_bfloat16* r1) {
  int t = blockIdx.x * 256 + threadIdx.x;
  if (t < 2048) {
    r0[16777216 + t] = __float2bfloat16(0.f);
    r1[16777216 + t] = __float2bfloat16(0.f);
  }
}

// ---------------------------------------------------------------- weight prepack into MFMA-fragment order
__global__ __launch_bounds__(256) void prepack_w(const float* __restrict__ w,
                                                 const float* __restrict__ invs,
                                                 __hip_bfloat16* __restrict__ dst,
                                                 int CINR, int COUT, int KPAD, int KREAL) {
  int e = blockIdx.x * 256 + threadIdx.x;
  if (e >= KPAD * COUT) return;
  int j = e & 7, lane = (e >> 3) & 63, frag = e >> 9;
  int nfrags = COUT >> 4;
  int ks = frag / nfrags, nf = frag - ks * nfrags;
  int k = ks * 32 + ((lane >> 4) << 3) + j;
  int co = (nf << 4) + (lane & 15);
  float val = 0.f;
  if (k < KREAL) {
    int khw = k / CINR, ci = k - khw * CINR;
    int kh = khw >> 2, kw = khw & 3;
    val = w[(((size_t)co * CINR + ci) * 4 + kh) * 4 + kw] * invs[0];
  }
  dst[e] = __float2bfloat16(val);
}

// ---------------------------------------------------------------- L1 im2col, coalesced 16B writes
// thread -> (m, chunk): 8 threads per output row, each computes 8 k-values and
// writes one bf16x8 (lane-consecutive 16B chunks -> 1KB contiguous per wave).
__global__ __launch_bounds__(256) void im2col_l1(const float* __restrict__ img,
                                                 __hip_bfloat16* __restrict__ a2) {
  int t = blockIdx.x * 256 + threadIdx.x;      // 2097152 = 262144 m * 8 chunks
  int c = t & 7;
  int m = t >> 3;
  int n = m >> 12;
  int hw = m & 4095;
  int ho = hw >> 6, wo = hw & 63;
  int ihb = 2 * ho - 1, iwb = 2 * wo - 1;
  const float* __restrict__ ib = img + (size_t)n * 49152;
  short vals[8];
  #pragma unroll
  for (int j = 0; j < 8; ++j) {
    int k = c * 8 + j;
    float val = 0.f;
    if (k < 48) {
      int khw = k / 3;
      int ci = k - khw * 3;
      int kh = khw >> 2, kw = khw & 3;
      int ih = ihb + kh, iw = iwb + kw;
      if (((unsigned)ih < 128u) & ((unsigned)iw < 128u))
        val = ib[ci * 16384 + ih * 128 + iw];
    }
    vals[j] = f2bf(val);
  }
  *(bf16x8*)(a2 + (size_t)m * 64 + c * 8) = *(bf16x8*)vals;
}

// ---------------------------------------------------------------- MFMA implicit-GEMM conv
template<int CIN, int COUT, int HIN, int HOUT, int KH, int MF, bool FUSE>
__global__ __launch_bounds__(256) void conv_mfma(
    const __hip_bfloat16* __restrict__ x,
    const __hip_bfloat16* __restrict__ wf,
    __hip_bfloat16* __restrict__ out)
{
  constexpr int WIN = HIN, WO = HOUT;
  constexpr int KHW = KH * KH;
  constexpr int CB = CIN / 32;
  constexpr int PADOFF = 16777216;

  const int lane = threadIdx.x & 63;
  const int wid  = threadIdx.x >> 6;
  const int wm = wid >> 1, wn = wid & 1;
  const int mbase = blockIdx.x * (MF * 32) + wm * (MF * 16);
  const int cobase = blockIdx.y * 64 + wn * 32;

  int offm[MF], ihb[MF], iwb[MF];
  #pragma unroll
  for (int mf = 0; mf < MF; ++mf) {
    int m = mbase + mf * 16 + (lane & 15);
    if (KH == 1) {
      ihb[mf] = 0; iwb[mf] = 0; offm[mf] = m * CIN;
    } else {
      int n = m / (HOUT * WO);
      int hw = m - n * (HOUT * WO);
      int ho = hw / WO, wo = hw - ho * WO;
      ihb[mf] = 2 * ho - 1;
      iwb[mf] = 2 * wo - 1;
      offm[mf] = ((n * HIN + ihb[mf]) * WIN + iwb[mf]) * CIN;
    }
  }
  const int koff = (lane >> 4) << 3;
  const __hip_bfloat16* wfp = wf + ((size_t)((blockIdx.y * 4 + wn * 2) * 64 + lane)) * 8;

  f32x4 acc[MF][2];
  #pragma unroll
  for (int mf = 0; mf < MF; ++mf) {
    acc[mf][0] = (f32x4){0.f, 0.f, 0.f, 0.f};
    acc[mf][1] = (f32x4){0.f, 0.f, 0.f, 0.f};
  }

  #pragma unroll
  for (int khw = 0; khw < KHW; ++khw) {
    const int kh = khw >> 2, kw = khw & 3;
    const __hip_bfloat16* ap[MF];
    #pragma unroll
    for (int mf = 0; mf < MF; ++mf) {
      int off;
      if (KH == 1) {
        off = offm[mf] + koff;
      } else {
        int ih = ihb[mf] + kh, iw = iwb[mf] + kw;
        bool v = ((unsigned)ih < (unsigned)HIN) & ((unsigned)iw < (unsigned)WIN);
        off = v ? (offm[mf] + (kh * WIN + kw) * CIN + koff) : (PADOFF + koff);
      }
      ap[mf] = x + off;
    }
    #pragma unroll
    for (int cb = 0; cb < CB; ++cb) {
      const int ks = khw * CB + cb;
      bf16x8 a[MF], b[2];
      #pragma unroll
      for (int mf = 0; mf < MF; ++mf) a[mf] = *(const bf16x8*)(ap[mf] + cb * 32);
      #pragma unroll
      for (int nf = 0; nf < 2; ++nf)
        b[nf] = *(const bf16x8*)(wfp + (size_t)ks * (COUT * 32) + nf * 512);
      #pragma unroll
      for (int mf = 0; mf < MF; ++mf)
        #pragma unroll
        for (int nf = 0; nf < 2; ++nf)
          acc[mf][nf] = __builtin_amdgcn_mfma_f32_16x16x32_bf16(a[mf], b[nf], acc[mf][nf], 0, 0, 0);
    }
  }

  const int r0 = (lane >> 4) * 4;
  const int cw = cobase + (lane & 15);
  #pragma unroll
  for (int mf = 0; mf < MF; ++mf)
    #pragma unroll
    for (int nf = 0; nf < 2; ++nf)
      #pragma unroll
      for (int r = 0; r < 4; ++r) {
        float v = acc[mf][nf][r];
        if (FUSE) v = (v >= 0.f) ? v : LRELU * v;
        int m = mbase + mf * 16 + r0 + r;
        out[(size_t)m * COUT + (cw + nf * 16)] = __float2bfloat16(v);
      }
}

// ---------------------------------------------------------------- L6 MFMA conv: x5 NHWC [64,4,4,512] -> x6 fp32 [n*256 + co*4 + p]
__global__ __launch_bounds__(256) void conv_l6_mfma(
    const __hip_bfloat16* __restrict__ x,
    const __hip_bfloat16* __restrict__ wf,
    float* __restrict__ x6)
{
  constexpr int CIN = 512, COUT = 64, HIN = 4;
  constexpr int CB = CIN / 32;
  constexpr int PADOFF = 16777216;

  const int lane = threadIdx.x & 63;
  const int wid  = threadIdx.x >> 6;
  const int wm = wid >> 1, wn = wid & 1;
  const int mbase = blockIdx.x * 32 + wm * 16;

  int m0 = mbase + (lane & 15);
  int n = m0 >> 2;
  int hw = m0 & 3;
  int ho = hw >> 1, wo = hw & 1;
  int ihb = 2 * ho - 1;
  int iwb = 2 * wo - 1;
  int offm = ((n * HIN + ihb) * HIN + iwb) * CIN;

  const int koff = (lane >> 4) << 3;
  const __hip_bfloat16* wfp = wf + ((size_t)((wn * 2) * 64 + lane)) * 8;

  f32x4 acc[2];
  acc[0] = (f32x4){0.f, 0.f, 0.f, 0.f};
  acc[1] = (f32x4){0.f, 0.f, 0.f, 0.f};

  #pragma unroll
  for (int khw = 0; khw < 16; ++khw) {
    const int kh = khw >> 2, kw = khw & 3;
    const int ih = ihb + kh, iw = iwb + kw;
    const bool v = ((unsigned)ih < (unsigned)HIN) & ((unsigned)iw < (unsigned)HIN);
    const int off = v ? (offm + (kh * HIN + kw) * CIN + koff) : (PADOFF + koff);
    const __hip_bfloat16* ap = x + off;
    #pragma unroll
    for (int cb = 0; cb < CB; ++cb) {
      const int ks = khw * CB + cb;
      bf16x8 a = *(const bf16x8*)(ap + cb * 32);
      bf16x8 b0 = *(const bf16x8*)(wfp + (size_t)ks * (COUT * 32));
      bf16x8 b1 = *(const bf16x8*)(wfp + (size_t)ks * (COUT * 32) + 512);
      acc[0] = __builtin_amdgcn_mfma_f32_16x16x32_bf16(a, b0, acc[0], 0, 0, 0);
      acc[1] = __builtin_amdgcn_mfma_f32_16x16x32_bf16(a, b1, acc[1], 0, 0, 0);
    }
  }

  const int r0 = (lane >> 4) * 4;
  const int cw = wn * 32 + (lane & 15);
  #pragma unroll
  for (int nf = 0; nf < 2; ++nf)
    #pragma unroll
    for (int r = 0; r < 4; ++r) {
      int m = mbase + r0 + r;
      int nn = m >> 2, p = m & 3;
      x6[(size_t)nn * 256 + (cw + nf * 16) * 4 + p] = acc[nf][r];
    }
}

// ---------------------------------------------------------------- BN stats (deterministic 2-stage), NHWC bf16
__global__ __launch_bounds__(256) void bn_stats_a(const __hip_bfloat16* __restrict__ x,
                                                  float* __restrict__ part, int M, int C) {
  const int chunk = blockIdx.x;
  const int c = blockIdx.y * 64 + (threadIdx.x & 63);
  const int msub = threadIdx.x >> 6;
  const int MC = M >> 6;
  float s = 0.f, s2 = 0.f;
  for (int mi = msub; mi < MC; mi += 4) {
    int m = chunk * MC + mi;
    float v = bf2f(*(const short*)&x[(size_t)m * C + c]);
    s += v;
    s2 = fmaf(v, v, s2);
  }
  __shared__ float ls[256], ls2[256];
  ls[threadIdx.x] = s; ls2[threadIdx.x] = s2;
  __syncthreads();
  if (msub == 0) {
    int t = threadIdx.x;
    s  = ls[t]  + ls[t + 64]  + ls[t + 128]  + ls[t + 192];
    s2 = ls2[t] + ls2[t + 64] + ls2[t + 128] + ls2[t + 192];
    part[(size_t)chunk * C + c] = s;
    part[(size_t)(64 + chunk) * C + c] = s2;
  }
}

__global__ __launch_bounds__(64) void bn_stats_b(const float* __restrict__ part,
                                                 const float* __restrict__ g,
                                                 const float* __restrict__ b,
                                                 float* __restrict__ sb, int M, int C) {
  int c = blockIdx.x * 64 + threadIdx.x;
  float s = 0.f, s2 = 0.f;
  for (int ch = 0; ch < 64; ++ch) { s += part[(size_t)ch * C + c]; s2 += part[(size_t)(64 + ch) * C + c]; }
  float invM = 1.f / (float)M;
  float mean = s * invM;
  float var = s2 * invM - mean * mean;
  float scale = g[c] * rsqrtf(var + BN_EPS);
  sb[c] = scale;
  sb[C + c] = b[c] - mean * scale;
}

__global__ __launch_bounds__(256) void bn_apply(__hip_bfloat16* __restrict__ x,
                                                const float* __restrict__ sb,
                                                int C, int nvec) {
  int idx = blockIdx.x * 256 + threadIdx.x;
  if (idx >= nvec) return;
  size_t e = (size_t)idx * 8;
  int c0 = (int)(e % (size_t)C);
  bf16x8 v = *(bf16x8*)(x + e);
  bf16x8 o;
  #pragma unroll
  for (int j = 0; j < 8; ++j) {
    int c = c0 + j;
    float f = bf2f(v[j]);
    f = fmaf(f, sb[c], sb[C + c]);
    f = (f >= 0.f) ? f : LRELU * f;
    o[j] = f2bf(f);
  }
  *(bf16x8*)(x + e) = o;
}

// ---------------------------------------------------------------- tail
__global__ __launch_bounds__(256) void ms_kernel(const float* __restrict__ x6, const float* __restrict__ T,
                                                 float* __restrict__ Ms, float* __restrict__ out) {
  const int n = blockIdx.x;
  const int tid = threadIdx.x;
  __shared__ float fs[256];
  const float f = x6[(size_t)n * 256 + tid];
  fs[tid] = f;
  out[(size_t)n * 320 + tid] = f;
  __syncthreads();
  float acc[16];
  #pragma unroll
  for (int k = 0; k < 16; ++k) acc[k] = 0.f;
  for (int a = 0; a < 256; ++a) {
    const float fa = fs[a];
    const float* __restrict__ Trow = T + (size_t)a * 4096 + tid;
    #pragma unroll
    for (int k = 0; k < 16; ++k) acc[k] = fmaf(fa, Trow[(size_t)k * 256], acc[k]);
  }
  #pragma unroll
  for (int k = 0; k < 16; ++k) Ms[(size_t)n * 4096 + tid + (size_t)k * 256] = acc[k];
}

__global__ __launch_bounds__(256) void mbd_kernel(const float* __restrict__ Ms, float* __restrict__ out) {
  const int b = blockIdx.x;
  const int tid = threadIdx.x;
  __shared__ float Mb[64][65];
  for (int idx = tid; idx < 4096; idx += 256) {
    const int i = idx >> 6, c = idx & 63;
    Mb[i][c] = Ms[(size_t)i * 4096 + b * 64 + c];
  }
  __syncthreads();
  const int i = tid >> 2, jj = tid & 3;
  float ssum = 0.f;
  for (int j = jj; j < 64; j += 4) {
    float d = 0.f;
    #pragma unroll
    for (int c = 0; c < 64; ++c) d += fabsf(Mb[i][c] - Mb[j][c]);
    ssum += expf(-d);
  }
  ssum += __shfl_xor(ssum, 1, 64);
  ssum += __shfl_xor(ssum, 2, 64);
  if (jj == 0) out[(size_t)i * 320 + 256 + b] = ssum;
}

// ---------------------------------------------------------------- launch
extern "C" void kernel_launch(void* const* d_in, const int* in_sizes, int n_in,
                              void* d_out, int out_size, void* d_ws, size_t ws_size,
                              hipStream_t stream) {
  const float* image = (const float*)d_in[0];
  const float* W[6] = {(const float*)d_in[1], (const float*)d_in[3], (const float*)d_in[5],
                       (const float*)d_in[7], (const float*)d_in[9], (const float*)d_in[11]};
  const float* U[6] = {(const float*)d_in[2], (const float*)d_in[4], (const float*)d_in[6],
                       (const float*)d_in[8], (const float*)d_in[10], (const float*)d_in[12]};
  const float* G[4] = {(const float*)d_in[13], (const float*)d_in[15],
                       (const float*)d_in[17], (const float*)d_in[19]};
  const float* Bb[4] = {(const float*)d_in[14], (const float*)d_in[16],
                        (const float*)d_in[18], (const float*)d_in[20]};
  const float* T = (const float*)d_in[21];
  float* out = (float*)d_out;

  // ---- workspace layout (floats)
  float* f = (float*)d_ws;
  float* inv_sigma = f;                                // 16
  float* part      = f + 1024;                         // 65536
  float* sb        = f + 1024 + 65536;                 // 1024
  float* x6        = f + 1024 + 65536 + 1024;          // 16384
  float* Ms        = f + 1024 + 65536 + 1024 + 16384;  // 262144
  float* vbuf      = f + 360448;                       // 49152
  float* pA        = f + 360448 + 49152;               // 192
  float* pB        = pA + 256;                         // 192
  float* rinv      = pB + 256;                         // 16
  __hip_bfloat16* bfb = (__hip_bfloat16*)(f + 524288);
  const size_t REGION = 16777216 + 2048;
  __hip_bfloat16* region0 = bfb;
  __hip_bfloat16* region1 = region0 + REGION;
  __hip_bfloat16* wf1 = region1 + REGION;
  __hip_bfloat16* wf2 = wf1 + 4096;
  __hip_bfloat16* wf3 = wf2 + 131072;
  __hip_bfloat16* wf4 = wf3 + 524288;
  __hip_bfloat16* wf5 = wf4 + 1048576;
  __hip_bfloat16* wf6 = wf5 + 2097152;

  __hip_bfloat16* a2col = region0;
  __hip_bfloat16* x1 = region1;
  __hip_bfloat16* x2 = region0;
  __hip_bfloat16* x3 = region1;
  __hip_bfloat16* x4 = region0;
  __hip_bfloat16* x5 = region1;

  zero_pads<<<8, 256, 0, stream>>>(region0, region1);

  SNArgs sa;
  const int outc[6] = {64, 128, 256, 256, 512, 64};
  const int ink[6]  = {48, 1024, 2048, 4096, 4096, 8192};
  for (int l = 0; l < 6; ++l) { sa.w[l] = W[l]; sa.u[l] = U[l]; sa.outc[l] = outc[l]; sa.ink[l] = ink[l]; }

  sn_v<<<dim3(32, 6), 256, 0, stream>>>(sa, vbuf, pA);
  sn_norm1<<<6, 64, 0, stream>>>(sa, pA, rinv);
  sn_t2<<<dim3(32, 6), 256, 0, stream>>>(sa, vbuf, rinv, pB);
  sn_norm2<<<6, 64, 0, stream>>>(pB, inv_sigma);

  prepack_w<<<16,    256, 0, stream>>>(W[0], inv_sigma + 0, wf1, 3,   64,  64,   48);
  prepack_w<<<512,   256, 0, stream>>>(W[1], inv_sigma + 1, wf2, 64,  128, 1024, 1024);
  prepack_w<<<2048,  256, 0, stream>>>(W[2], inv_sigma + 2, wf3, 128, 256, 2048, 2048);
  prepack_w<<<4096,  256, 0, stream>>>(W[3], inv_sigma + 3, wf4, 256, 256, 4096, 4096);
  prepack_w<<<8192,  256, 0, stream>>>(W[4], inv_sigma + 4, wf5, 256, 512, 4096, 4096);
  prepack_w<<<2048,  256, 0, stream>>>(W[5], inv_sigma + 5, wf6, 512, 64,  8192, 8192);

  im2col_l1<<<8192, 256, 0, stream>>>(image, a2col);

  conv_mfma<64, 64, 1, 1, 1, 4, true><<<dim3(2048, 1), 256, 0, stream>>>(a2col, wf1, x1);

  auto bn = [&](__hip_bfloat16* x, int bi, int M, int C) {
    bn_stats_a<<<dim3(64, C / 64), 256, 0, stream>>>(x, part, M, C);
    bn_stats_b<<<C / 64, 64, 0, stream>>>(part, G[bi], Bb[bi], sb, M, C);
    int nvec = M * C / 8;
    bn_apply<<<(nvec + 255) / 256, 256, 0, stream>>>(x, sb, C, nvec);
  };

  conv_mfma<64, 128, 64, 32, 4, 4, false><<<dim3(512, 2), 256, 0, stream>>>(x1, wf2, x2);
  bn(x2, 0, 65536, 128);
  conv_mfma<128, 256, 32, 16, 4, 4, false><<<dim3(128, 4), 256, 0, stream>>>(x2, wf3, x3);
  bn(x3, 1, 16384, 256);
  conv_mfma<256, 256, 16, 8, 4, 2, false><<<dim3(64, 4), 256, 0, stream>>>(x3, wf4, x4);
  bn(x4, 2, 4096, 256);
  conv_mfma<256, 512, 8, 4, 4, 1, false><<<dim3(32, 8), 256, 0, stream>>>(x4, wf5, x5);
  bn(x5, 3, 1024, 512);
  conv_l6_mfma<<<8, 256, 0, stream>>>(x5, wf6, x6);

  ms_kernel<<<64, 256, 0, stream>>>(x6, T, Ms, out);
  mbd_kernel<<<64, 256, 0, stream>>>(Ms, out);
}

// Round 6
// 585.531 us; speedup vs baseline: 13.6513x; 1.1184x over previous
//
#include <hip/hip_runtime.h>
#include <hip/hip_bf16.h>
#include <math.h>

#define LRELU 0.2f
#define BN_EPS 1e-5f
#define SN_EPS 1e-12f

typedef __attribute__((ext_vector_type(4))) float f32x4;
typedef __attribute__((ext_vector_type(8))) short bf16x8;
typedef __attribute__((ext_vector_type(4))) short bf16x4;

__device__ inline float bf2f(short s) {
  union { unsigned u; float f; } c; c.u = ((unsigned)(unsigned short)s) << 16; return c.f;
}
__device__ inline short f2bf(float f) {
  __hip_bfloat16 h = __float2bfloat16(f); return *(short*)&h;
}

// ---------------------------------------------------------------- reductions
__device__ inline float blockReduceSum256(float v, volatile float* red) {
  #pragma unroll
  for (int o = 32; o > 0; o >>= 1) v += __shfl_down(v, o, 64);
  const int tid = threadIdx.x;
  __syncthreads();
  if ((tid & 63) == 0) red[tid >> 6] = v;
  __syncthreads();
  return red[0] + red[1] + red[2] + red[3];
}

// ---------------------------------------------------------------- spectral norm, parallel 4-stage chain
struct SNArgs {
  const float* w[6];
  const float* u[6];
  int outc[6];
  int ink[6];
};

__global__ __launch_bounds__(256) void sn_v(SNArgs args, float* __restrict__ vbuf,
                                            float* __restrict__ pA) {
  const int l = blockIdx.y;
  const int in_k = args.ink[l], out_c = args.outc[l];
  const int tid = threadIdx.x;
  const int j = blockIdx.x * 256 + tid;
  __shared__ float uS[512];
  __shared__ float red[4];
  for (int i = tid; i < out_c; i += 256) uS[i] = args.u[l][i];
  __syncthreads();
  float t = 0.f;
  if (j < in_k) {
    const float* __restrict__ w = args.w[l];
    #pragma unroll 4
    for (int i = 0; i < out_c; ++i) t = fmaf(w[(size_t)i * in_k + j], uS[i], t);
    vbuf[l * 8192 + j] = t;
  }
  const float bs = blockReduceSum256((j < in_k) ? t * t : 0.f, red);
  if (tid == 0) pA[l * 32 + blockIdx.x] = bs;
}

__global__ __launch_bounds__(64) void sn_norm1(SNArgs args, const float* __restrict__ pA,
                                               float* __restrict__ rinv) {
  const int l = blockIdx.x;
  if (threadIdx.x != 0) return;
  const int nb = (args.ink[l] + 255) >> 8;
  float s = 0.f;
  for (int b = 0; b < nb; ++b) s += pA[l * 32 + b];
  rinv[l] = 1.f / (sqrtf(s) + SN_EPS);
}

__global__ __launch_bounds__(256) void sn_t2(SNArgs args, const float* __restrict__ vbuf,
                                             const float* __restrict__ rinv,
                                             float* __restrict__ pB) {
  const int l = blockIdx.y;
  const int in_k = args.ink[l], out_c = args.outc[l];
  const int tid = threadIdx.x;
  const int lane = tid & 63, wv = tid >> 6;
  const float* __restrict__ W = args.w[l];
  const float* __restrict__ v = vbuf + l * 8192;
  const float r = rinv[l];
  float sqacc = 0.f;
  for (int row = blockIdx.x * 4 + wv; row < out_c; row += 128) {
    float t = 0.f;
    const float* __restrict__ wr = W + (size_t)row * in_k;
    for (int j = lane; j < in_k; j += 64) t = fmaf(wr[j], v[j], t);
    #pragma unroll
    for (int o = 32; o > 0; o >>= 1) t += __shfl_down(t, o, 64);
    if (lane == 0) { t *= r; sqacc = fmaf(t, t, sqacc); }
  }
  __shared__ float red[4];
  __syncthreads();
  if (lane == 0) red[wv] = sqacc;
  __syncthreads();
  if (tid == 0) pB[l * 32 + blockIdx.x] = red[0] + red[1] + red[2] + red[3];
}

__global__ __launch_bounds__(64) void sn_norm2(const float* __restrict__ pB,
                                               float* __restrict__ inv_sigma) {
  const int l = blockIdx.x;
  if (threadIdx.x != 0) return;
  float s = 0.f;
  for (int b = 0; b < 32; ++b) s += pB[l * 32 + b];
  const float n2 = sqrtf(s);
  const float sigma = s / (n2 + SN_EPS);
  inv_sigma[l] = 1.f / sigma;
}

// ---------------------------------------------------------------- zero the OOB pad regions
__global__ __launch_bounds__(256) void zero_pads(__hip_bfloat16* r0, __hip_bfloat16* r1) {
  int t = blockIdx.x * 256 + threadIdx.x;
  if (t < 2048) {
    r0[16777216 + t] = __float2bfloat16(0.f);
    r1[16777216 + t] = __float2bfloat16(0.f);
  }
}

// ---------------------------------------------------------------- weight prepack into MFMA-fragment order
__global__ __launch_bounds__(256) void prepack_w(const float* __restrict__ w,
                                                 const float* __restrict__ invs,
                                                 __hip_bfloat16* __restrict__ dst,
                                                 int CINR, int COUT, int KPAD, int KREAL) {
  int e = blockIdx.x * 256 + threadIdx.x;
  if (e >= KPAD * COUT) return;
  int j = e & 7, lane = (e >> 3) & 63, frag = e >> 9;
  int nfrags = COUT >> 4;
  int ks = frag / nfrags, nf = frag - ks * nfrags;
  int k = ks * 32 + ((lane >> 4) << 3) + j;
  int co = (nf << 4) + (lane & 15);
  float val = 0.f;
  if (k < KREAL) {
    int khw = k / CINR, ci = k - khw * CINR;
    int kh = khw >> 2, kw = khw & 3;
    val = w[(((size_t)co * CINR + ci) * 4 + kh) * 4 + kw] * invs[0];
  }
  dst[e] = __float2bfloat16(val);
}

// ---------------------------------------------------------------- L1 im2col, coalesced 16B writes
__global__ __launch_bounds__(256) void im2col_l1(const float* __restrict__ img,
                                                 __hip_bfloat16* __restrict__ a2) {
  int t = blockIdx.x * 256 + threadIdx.x;      // 2097152
  int c = t & 7;
  int m = t >> 3;
  int n = m >> 12;
  int hw = m & 4095;
  int ho = hw >> 6, wo = hw & 63;
  int ihb = 2 * ho - 1, iwb = 2 * wo - 1;
  const float* __restrict__ ib = img + (size_t)n * 49152;
  short vals[8];
  #pragma unroll
  for (int j = 0; j < 8; ++j) {
    int k = c * 8 + j;
    float val = 0.f;
    if (k < 48) {
      int khw = k / 3;
      int ci = k - khw * 3;
      int kh = khw >> 2, kw = khw & 3;
      int ih = ihb + kh, iw = iwb + kw;
      if (((unsigned)ih < 128u) & ((unsigned)iw < 128u))
        val = ib[ci * 16384 + ih * 128 + iw];
    }
    vals[j] = f2bf(val);
  }
  *(bf16x8*)(a2 + (size_t)m * 64 + c * 8) = *(bf16x8*)vals;
}

// ---------------------------------------------------------------- MFMA implicit-GEMM conv
template<int CIN, int COUT, int HIN, int HOUT, int KH, int MF, bool FUSE>
__global__ __launch_bounds__(256) void conv_mfma(
    const __hip_bfloat16* __restrict__ x,
    const __hip_bfloat16* __restrict__ wf,
    __hip_bfloat16* __restrict__ out)
{
  constexpr int WIN = HIN, WO = HOUT;
  constexpr int KHW = KH * KH;
  constexpr int CB = CIN / 32;
  constexpr int PADOFF = 16777216;

  const int lane = threadIdx.x & 63;
  const int wid  = threadIdx.x >> 6;
  const int wm = wid >> 1, wn = wid & 1;
  const int mbase = blockIdx.x * (MF * 32) + wm * (MF * 16);
  const int cobase = blockIdx.y * 64 + wn * 32;

  int offm[MF], ihb[MF], iwb[MF];
  #pragma unroll
  for (int mf = 0; mf < MF; ++mf) {
    int m = mbase + mf * 16 + (lane & 15);
    if (KH == 1) {
      ihb[mf] = 0; iwb[mf] = 0; offm[mf] = m * CIN;
    } else {
      int n = m / (HOUT * WO);
      int hw = m - n * (HOUT * WO);
      int ho = hw / WO, wo = hw - ho * WO;
      ihb[mf] = 2 * ho - 1;
      iwb[mf] = 2 * wo - 1;
      offm[mf] = ((n * HIN + ihb[mf]) * WIN + iwb[mf]) * CIN;
    }
  }
  const int koff = (lane >> 4) << 3;
  const __hip_bfloat16* wfp = wf + ((size_t)((blockIdx.y * 4 + wn * 2) * 64 + lane)) * 8;

  f32x4 acc[MF][2];
  #pragma unroll
  for (int mf = 0; mf < MF; ++mf) {
    acc[mf][0] = (f32x4){0.f, 0.f, 0.f, 0.f};
    acc[mf][1] = (f32x4){0.f, 0.f, 0.f, 0.f};
  }

  #pragma unroll
  for (int khw = 0; khw < KHW; ++khw) {
    const int kh = khw >> 2, kw = khw & 3;
    const __hip_bfloat16* ap[MF];
    #pragma unroll
    for (int mf = 0; mf < MF; ++mf) {
      int off;
      if (KH == 1) {
        off = offm[mf] + koff;
      } else {
        int ih = ihb[mf] + kh, iw = iwb[mf] + kw;
        bool v = ((unsigned)ih < (unsigned)HIN) & ((unsigned)iw < (unsigned)WIN);
        off = v ? (offm[mf] + (kh * WIN + kw) * CIN + koff) : (PADOFF + koff);
      }
      ap[mf] = x + off;
    }
    #pragma unroll
    for (int cb = 0; cb < CB; ++cb) {
      const int ks = khw * CB + cb;
      bf16x8 a[MF], b[2];
      #pragma unroll
      for (int mf = 0; mf < MF; ++mf) a[mf] = *(const bf16x8*)(ap[mf] + cb * 32);
      #pragma unroll
      for (int nf = 0; nf < 2; ++nf)
        b[nf] = *(const bf16x8*)(wfp + (size_t)ks * (COUT * 32) + nf * 512);
      #pragma unroll
      for (int mf = 0; mf < MF; ++mf)
        #pragma unroll
        for (int nf = 0; nf < 2; ++nf)
          acc[mf][nf] = __builtin_amdgcn_mfma_f32_16x16x32_bf16(a[mf], b[nf], acc[mf][nf], 0, 0, 0);
    }
  }

  const int r0 = (lane >> 4) * 4;
  const int cw = cobase + (lane & 15);
  #pragma unroll
  for (int mf = 0; mf < MF; ++mf)
    #pragma unroll
    for (int nf = 0; nf < 2; ++nf)
      #pragma unroll
      for (int r = 0; r < 4; ++r) {
        float v = acc[mf][nf][r];
        if (FUSE) v = (v >= 0.f) ? v : LRELU * v;
        int m = mbase + mf * 16 + r0 + r;
        out[(size_t)m * COUT + (cw + nf * 16)] = __float2bfloat16(v);
      }
}

// ---------------------------------------------------------------- split-K MFMA conv (khw chunks), fp32 partials
template<int CIN, int COUT, int HIN, int HOUT, int MF, int Z>
__global__ __launch_bounds__(256) void conv_mfma_sk(
    const __hip_bfloat16* __restrict__ x,
    const __hip_bfloat16* __restrict__ wf,
    float* __restrict__ part)
{
  constexpr int WIN = HIN, WO = HOUT;
  constexpr int CB = CIN / 32;
  constexpr int PADOFF = 16777216;
  constexpr int KHW_PER = 16 / Z;
  constexpr int M = 64 * HOUT * HOUT;

  const int lane = threadIdx.x & 63;
  const int wid  = threadIdx.x >> 6;
  const int wm = wid >> 1, wn = wid & 1;
  const int mbase = blockIdx.x * (MF * 32) + wm * (MF * 16);
  const int cobase = blockIdx.y * 64 + wn * 32;
  const int khw0 = blockIdx.z * KHW_PER;

  int offm[MF], ihb[MF], iwb[MF];
  #pragma unroll
  for (int mf = 0; mf < MF; ++mf) {
    int m = mbase + mf * 16 + (lane & 15);
    int n = m / (HOUT * WO);
    int hw = m - n * (HOUT * WO);
    int ho = hw / WO, wo = hw - ho * WO;
    ihb[mf] = 2 * ho - 1;
    iwb[mf] = 2 * wo - 1;
    offm[mf] = ((n * HIN + ihb[mf]) * WIN + iwb[mf]) * CIN;
  }
  const int koff = (lane >> 4) << 3;
  const __hip_bfloat16* wfp = wf + ((size_t)((blockIdx.y * 4 + wn * 2) * 64 + lane)) * 8;

  f32x4 acc[MF][2];
  #pragma unroll
  for (int mf = 0; mf < MF; ++mf) {
    acc[mf][0] = (f32x4){0.f, 0.f, 0.f, 0.f};
    acc[mf][1] = (f32x4){0.f, 0.f, 0.f, 0.f};
  }

  #pragma unroll
  for (int ki = 0; ki < KHW_PER; ++ki) {
    const int khw = khw0 + ki;
    const int kh = khw >> 2, kw = khw & 3;
    const __hip_bfloat16* ap[MF];
    #pragma unroll
    for (int mf = 0; mf < MF; ++mf) {
      int ih = ihb[mf] + kh, iw = iwb[mf] + kw;
      bool v = ((unsigned)ih < (unsigned)HIN) & ((unsigned)iw < (unsigned)WIN);
      int off = v ? (offm[mf] + (kh * WIN + kw) * CIN + koff) : (PADOFF + koff);
      ap[mf] = x + off;
    }
    #pragma unroll
    for (int cb = 0; cb < CB; ++cb) {
      const int ks = khw * CB + cb;
      bf16x8 a[MF], b[2];
      #pragma unroll
      for (int mf = 0; mf < MF; ++mf) a[mf] = *(const bf16x8*)(ap[mf] + cb * 32);
      #pragma unroll
      for (int nf = 0; nf < 2; ++nf)
        b[nf] = *(const bf16x8*)(wfp + (size_t)ks * (COUT * 32) + nf * 512);
      #pragma unroll
      for (int mf = 0; mf < MF; ++mf)
        #pragma unroll
        for (int nf = 0; nf < 2; ++nf)
          acc[mf][nf] = __builtin_amdgcn_mfma_f32_16x16x32_bf16(a[mf], b[nf], acc[mf][nf], 0, 0, 0);
    }
  }

  const int r0 = (lane >> 4) * 4;
  const int cw = cobase + (lane & 15);
  float* __restrict__ pz = part + (size_t)blockIdx.z * M * COUT;
  #pragma unroll
  for (int mf = 0; mf < MF; ++mf)
    #pragma unroll
    for (int nf = 0; nf < 2; ++nf)
      #pragma unroll
      for (int r = 0; r < 4; ++r) {
        int m = mbase + mf * 16 + r0 + r;
        pz[(size_t)m * COUT + (cw + nf * 16)] = acc[mf][nf][r];
      }
}

// fixed-order reduce of Z fp32 partial slices -> bf16
template<int Z>
__global__ __launch_bounds__(256) void sk_reduce(const float* __restrict__ part,
                                                 __hip_bfloat16* __restrict__ xo, int MC4) {
  int idx = blockIdx.x * 256 + threadIdx.x;
  if (idx >= MC4) return;
  const size_t MC = (size_t)MC4 * 4;
  f32x4 s = *(const f32x4*)(part + (size_t)idx * 4);
  #pragma unroll
  for (int z = 1; z < Z; ++z)
    s += *(const f32x4*)(part + (size_t)z * MC + (size_t)idx * 4);
  bf16x4 o;
  #pragma unroll
  for (int j = 0; j < 4; ++j) o[j] = f2bf(s[j]);
  *(bf16x4*)(xo + (size_t)idx * 4) = o;
}

// ---------------------------------------------------------------- L6 MFMA conv; also writes flat part of out
__global__ __launch_bounds__(256) void conv_l6_mfma(
    const __hip_bfloat16* __restrict__ x,
    const __hip_bfloat16* __restrict__ wf,
    float* __restrict__ x6, float* __restrict__ out)
{
  constexpr int CIN = 512, COUT = 64, HIN = 4;
  constexpr int CB = CIN / 32;
  constexpr int PADOFF = 16777216;

  const int lane = threadIdx.x & 63;
  const int wid  = threadIdx.x >> 6;
  const int wm = wid >> 1, wn = wid & 1;
  const int mbase = blockIdx.x * 32 + wm * 16;

  int m0 = mbase + (lane & 15);
  int n = m0 >> 2;
  int hw = m0 & 3;
  int ho = hw >> 1, wo = hw & 1;
  int ihb = 2 * ho - 1;
  int iwb = 2 * wo - 1;
  int offm = ((n * HIN + ihb) * HIN + iwb) * CIN;

  const int koff = (lane >> 4) << 3;
  const __hip_bfloat16* wfp = wf + ((size_t)((wn * 2) * 64 + lane)) * 8;

  f32x4 acc[2];
  acc[0] = (f32x4){0.f, 0.f, 0.f, 0.f};
  acc[1] = (f32x4){0.f, 0.f, 0.f, 0.f};

  #pragma unroll
  for (int khw = 0; khw < 16; ++khw) {
    const int kh = khw >> 2, kw = khw & 3;
    const int ih = ihb + kh, iw = iwb + kw;
    const bool v = ((unsigned)ih < (unsigned)HIN) & ((unsigned)iw < (unsigned)HIN);
    const int off = v ? (offm + (kh * HIN + kw) * CIN + koff) : (PADOFF + koff);
    const __hip_bfloat16* ap = x + off;
    #pragma unroll
    for (int cb = 0; cb < CB; ++cb) {
      const int ks = khw * CB + cb;
      bf16x8 a = *(const bf16x8*)(ap + cb * 32);
      bf16x8 b0 = *(const bf16x8*)(wfp + (size_t)ks * (COUT * 32));
      bf16x8 b1 = *(const bf16x8*)(wfp + (size_t)ks * (COUT * 32) + 512);
      acc[0] = __builtin_amdgcn_mfma_f32_16x16x32_bf16(a, b0, acc[0], 0, 0, 0);
      acc[1] = __builtin_amdgcn_mfma_f32_16x16x32_bf16(a, b1, acc[1], 0, 0, 0);
    }
  }

  const int r0 = (lane >> 4) * 4;
  const int cw = wn * 32 + (lane & 15);
  #pragma unroll
  for (int nf = 0; nf < 2; ++nf)
    #pragma unroll
    for (int r = 0; r < 4; ++r) {
      int m = mbase + r0 + r;
      int nn = m >> 2, p = m & 3;
      float v = acc[nf][r];
      x6[(size_t)nn * 256 + (cw + nf * 16) * 4 + p] = v;
      out[(size_t)nn * 320 + (cw + nf * 16) * 4 + p] = v;
    }
}

// ---------------------------------------------------------------- BN stats (deterministic 2-stage), NHWC bf16
__global__ __launch_bounds__(256) void bn_stats_a(const __hip_bfloat16* __restrict__ x,
                                                  float* __restrict__ part, int M, int C) {
  const int chunk = blockIdx.x;
  const int c = blockIdx.y * 64 + (threadIdx.x & 63);
  const int msub = threadIdx.x >> 6;
  const int MC = M >> 6;
  float s = 0.f, s2 = 0.f;
  for (int mi = msub; mi < MC; mi += 4) {
    int m = chunk * MC + mi;
    float v = bf2f(*(const short*)&x[(size_t)m * C + c]);
    s += v;
    s2 = fmaf(v, v, s2);
  }
  __shared__ float ls[256], ls2[256];
  ls[threadIdx.x] = s; ls2[threadIdx.x] = s2;
  __syncthreads();
  if (msub == 0) {
    int t = threadIdx.x;
    s  = ls[t]  + ls[t + 64]  + ls[t + 128]  + ls[t + 192];
    s2 = ls2[t] + ls2[t + 64] + ls2[t + 128] + ls2[t + 192];
    part[(size_t)chunk * C + c] = s;
    part[(size_t)(64 + chunk) * C + c] = s2;
  }
}

__global__ __launch_bounds__(64) void bn_stats_b(const float* __restrict__ part,
                                                 const float* __restrict__ g,
                                                 const float* __restrict__ b,
                                                 float* __restrict__ sb, int M, int C) {
  int c = blockIdx.x * 64 + threadIdx.x;
  float s = 0.f, s2 = 0.f;
  for (int ch = 0; ch < 64; ++ch) { s += part[(size_t)ch * C + c]; s2 += part[(size_t)(64 + ch) * C + c]; }
  float invM = 1.f / (float)M;
  float mean = s * invM;
  float var = s2 * invM - mean * mean;
  float scale = g[c] * rsqrtf(var + BN_EPS);
  sb[c] = scale;
  sb[C + c] = b[c] - mean * scale;
}

__global__ __launch_bounds__(256) void bn_apply(__hip_bfloat16* __restrict__ x,
                                                const float* __restrict__ sb,
                                                int C, int nvec) {
  int idx = blockIdx.x * 256 + threadIdx.x;
  if (idx >= nvec) return;
  size_t e = (size_t)idx * 8;
  int c0 = (int)(e % (size_t)C);
  bf16x8 v = *(bf16x8*)(x + e);
  bf16x8 o;
  #pragma unroll
  for (int j = 0; j < 8; ++j) {
    int c = c0 + j;
    float f = bf2f(v[j]);
    f = fmaf(f, sb[c], sb[C + c]);
    f = (f >= 0.f) ? f : LRELU * f;
    o[j] = f2bf(f);
  }
  *(bf16x8*)(x + e) = o;
}

// ---------------------------------------------------------------- tail: Ms = flat @ T (256 blocks)
__global__ __launch_bounds__(256) void ms_kernel(const float* __restrict__ x6,
                                                 const float* __restrict__ T,
                                                 float* __restrict__ Ms) {
  const int cb = blockIdx.x;          // 64 col-chunks of 64
  const int nb = blockIdx.y;          // 4 n-chunks of 16
  const int c  = threadIdx.x & 63;
  const int ns = threadIdx.x >> 6;    // wave id -> n-subchunk
  __shared__ float fsh[16][256];
  for (int t = threadIdx.x; t < 4096; t += 256) {
    int n = t >> 8, a = t & 255;
    fsh[n][a] = x6[(size_t)(nb * 16 + n) * 256 + a];
  }
  __syncthreads();
  const int col = cb * 64 + c;
  float acc0 = 0.f, acc1 = 0.f, acc2 = 0.f, acc3 = 0.f;
  #pragma unroll 8
  for (int a = 0; a < 256; ++a) {
    float tv = T[(size_t)a * 4096 + col];
    acc0 = fmaf(fsh[ns * 4 + 0][a], tv, acc0);
    acc1 = fmaf(fsh[ns * 4 + 1][a], tv, acc1);
    acc2 = fmaf(fsh[ns * 4 + 2][a], tv, acc2);
    acc3 = fmaf(fsh[ns * 4 + 3][a], tv, acc3);
  }
  const int nbase = nb * 16 + ns * 4;
  Ms[(size_t)(nbase + 0) * 4096 + col] = acc0;
  Ms[(size_t)(nbase + 1) * 4096 + col] = acc1;
  Ms[(size_t)(nbase + 2) * 4096 + col] = acc2;
  Ms[(size_t)(nbase + 3) * 4096 + col] = acc3;
}

// ---------------------------------------------------------------- minibatch discrimination (256 blocks)
__global__ __launch_bounds__(256) void mbd_kernel(const float* __restrict__ Ms,
                                                  float* __restrict__ out) {
  const int b  = blockIdx.x;          // 64 features
  const int ib = blockIdx.y;          // 4 i-chunks of 16
  const int tid = threadIdx.x;
  __shared__ float Mb[64][65];
  for (int idx = tid; idx < 4096; idx += 256) {
    const int i = idx >> 6, cc = idx & 63;
    Mb[i][cc] = Ms[(size_t)i * 4096 + b * 64 + cc];
  }
  __syncthreads();
  const int i  = ib * 16 + (tid >> 4);
  const int jg = tid & 15;
  float ssum = 0.f;
  for (int j = jg; j < 64; j += 16) {
    float d = 0.f;
    #pragma unroll
    for (int cc = 0; cc < 64; ++cc) d += fabsf(Mb[i][cc] - Mb[j][cc]);
    ssum += expf(-d);
  }
  ssum += __shfl_xor(ssum, 1, 64);
  ssum += __shfl_xor(ssum, 2, 64);
  ssum += __shfl_xor(ssum, 4, 64);
  ssum += __shfl_xor(ssum, 8, 64);
  if (jg == 0) out[(size_t)i * 320 + 256 + b] = ssum;
}

// ---------------------------------------------------------------- launch
extern "C" void kernel_launch(void* const* d_in, const int* in_sizes, int n_in,
                              void* d_out, int out_size, void* d_ws, size_t ws_size,
                              hipStream_t stream) {
  const float* image = (const float*)d_in[0];
  const float* W[6] = {(const float*)d_in[1], (const float*)d_in[3], (const float*)d_in[5],
                       (const float*)d_in[7], (const float*)d_in[9], (const float*)d_in[11]};
  const float* U[6] = {(const float*)d_in[2], (const float*)d_in[4], (const float*)d_in[6],
                       (const float*)d_in[8], (const float*)d_in[10], (const float*)d_in[12]};
  const float* G[4] = {(const float*)d_in[13], (const float*)d_in[15],
                       (const float*)d_in[17], (const float*)d_in[19]};
  const float* Bb[4] = {(const float*)d_in[14], (const float*)d_in[16],
                        (const float*)d_in[18], (const float*)d_in[20]};
  const float* T = (const float*)d_in[21];
  float* out = (float*)d_out;

  // ---- workspace layout (floats)
  float* f = (float*)d_ws;
  float* inv_sigma = f;                                // 16
  float* part      = f + 1024;                         // 65536
  float* sb        = f + 1024 + 65536;                 // 1024
  float* x6        = f + 1024 + 65536 + 1024;          // 16384
  float* Ms        = f + 1024 + 65536 + 1024 + 16384;  // 262144
  float* vbuf      = f + 360448;                       // 49152
  float* pA        = f + 360448 + 49152;               // 192
  float* pB        = pA + 256;                         // 192
  float* rinv      = pB + 256;                         // 16
  __hip_bfloat16* bfb = (__hip_bfloat16*)(f + 524288);
  const size_t REGION = 16777216 + 2048;
  __hip_bfloat16* region0 = bfb;
  __hip_bfloat16* region1 = region0 + REGION;
  __hip_bfloat16* wf1 = region1 + REGION;
  __hip_bfloat16* wf2 = wf1 + 4096;
  __hip_bfloat16* wf3 = wf2 + 131072;
  __hip_bfloat16* wf4 = wf3 + 524288;
  __hip_bfloat16* wf5 = wf4 + 1048576;
  __hip_bfloat16* wf6 = wf5 + 2097152;
  float* skpart = (float*)(wf6 + 524288);              // 4*4096*256 fp32 = 16.8 MB max

  __hip_bfloat16* a2col = region0;
  __hip_bfloat16* x1 = region1;
  __hip_bfloat16* x2 = region0;
  __hip_bfloat16* x3 = region1;
  __hip_bfloat16* x4 = region0;
  __hip_bfloat16* x5 = region1;

  zero_pads<<<8, 256, 0, stream>>>(region0, region1);

  SNArgs sa;
  const int outc[6] = {64, 128, 256, 256, 512, 64};
  const int ink[6]  = {48, 1024, 2048, 4096, 4096, 8192};
  for (int l = 0; l < 6; ++l) { sa.w[l] = W[l]; sa.u[l] = U[l]; sa.outc[l] = outc[l]; sa.ink[l] = ink[l]; }

  sn_v<<<dim3(32, 6), 256, 0, stream>>>(sa, vbuf, pA);
  sn_norm1<<<6, 64, 0, stream>>>(sa, pA, rinv);
  sn_t2<<<dim3(32, 6), 256, 0, stream>>>(sa, vbuf, rinv, pB);
  sn_norm2<<<6, 64, 0, stream>>>(pB, inv_sigma);

  prepack_w<<<16,    256, 0, stream>>>(W[0], inv_sigma + 0, wf1, 3,   64,  64,   48);
  prepack_w<<<512,   256, 0, stream>>>(W[1], inv_sigma + 1, wf2, 64,  128, 1024, 1024);
  prepack_w<<<2048,  256, 0, stream>>>(W[2], inv_sigma + 2, wf3, 128, 256, 2048, 2048);
  prepack_w<<<4096,  256, 0, stream>>>(W[3], inv_sigma + 3, wf4, 256, 256, 4096, 4096);
  prepack_w<<<8192,  256, 0, stream>>>(W[4], inv_sigma + 4, wf5, 256, 512, 4096, 4096);
  prepack_w<<<2048,  256, 0, stream>>>(W[5], inv_sigma + 5, wf6, 512, 64,  8192, 8192);

  im2col_l1<<<8192, 256, 0, stream>>>(image, a2col);

  conv_mfma<64, 64, 1, 1, 1, 4, true><<<dim3(2048, 1), 256, 0, stream>>>(a2col, wf1, x1);

  auto bn = [&](__hip_bfloat16* x, int bi, int M, int C) {
    bn_stats_a<<<dim3(64, C / 64), 256, 0, stream>>>(x, part, M, C);
    bn_stats_b<<<C / 64, 64, 0, stream>>>(part, G[bi], Bb[bi], sb, M, C);
    int nvec = M * C / 8;
    bn_apply<<<(nvec + 255) / 256, 256, 0, stream>>>(x, sb, C, nvec);
  };

  // L2: 1024 blocks
  conv_mfma<64, 128, 64, 32, 4, 4, false><<<dim3(512, 2), 256, 0, stream>>>(x1, wf2, x2);
  bn(x2, 0, 65536, 128);
  // L3: MF=2 -> 1024 blocks
  conv_mfma<128, 256, 32, 16, 4, 2, false><<<dim3(256, 4), 256, 0, stream>>>(x2, wf3, x3);
  bn(x3, 1, 16384, 256);
  // L4: split-K Z=4 -> 1024 blocks, fp32 partials + reduce
  conv_mfma_sk<256, 256, 16, 8, 2, 4><<<dim3(64, 4, 4), 256, 0, stream>>>(x3, wf4, skpart);
  sk_reduce<4><<<1024, 256, 0, stream>>>(skpart, x4, 262144);
  bn(x4, 2, 4096, 256);
  // L5: split-K Z=4 -> 1024 blocks
  conv_mfma_sk<256, 512, 8, 4, 1, 4><<<dim3(32, 8, 4), 256, 0, stream>>>(x4, wf5, skpart);
  sk_reduce<4><<<512, 256, 0, stream>>>(skpart, x5, 131072);
  bn(x5, 3, 1024, 512);
  // L6 (+ writes flat part of out)
  conv_l6_mfma<<<8, 256, 0, stream>>>(x5, wf6, x6, out);

  ms_kernel<<<dim3(64, 4), 256, 0, stream>>>(x6, T, Ms);
  mbd_kernel<<<dim3(64, 4), 256, 0, stream>>>(Ms, out);
}